// Round 2
// baseline (4512.021 us; speedup 1.0000x reference)
//
#include <hip/hip_runtime.h>
#include <math.h>

#ifndef M_PI
#define M_PI 3.14159265358979323846
#endif

#define BBc 4
#define CCc 32
#define NRk 16
#define HHc 192
#define WWc 192
#define HWc 36864
#define DDi 1179648
#define M1c 12
#define EPSc 1e-5f

static const size_t DDs = (size_t)DDi;

// ---------------- workspace layout (floats) ----------------
#define SZ_T   ((size_t)4718592)       // B*C*HW  (= B*D)
#define SZ_ZC  ((size_t)589824)        // B*C*H*12*2
#define SZ_ZF  ((size_t)73728)         // B*C*24*12*2
#define SZ_WT  ((size_t)589824)        // 24*12*32*32*2
#define SZ_TAB ((size_t)4992)          // 13*192*2

#define OFF_XC   ((size_t)0)                  // xcur      (B*D)
#define OFF_XI   (OFF_XC + SZ_T)              // xi        (B*D)
#define OFF_F    (OFF_XI + SZ_T)              // F history [slot][B][D], 5 slots
#define OFF_G    (OFF_F + 5 * SZ_T)           // G history [slot][B][D], 5 slots
#define OFF_ZC   (OFF_G + 5 * SZ_T)
#define OFF_ZF   (OFF_ZC + SZ_ZC)
#define OFF_MO   (OFF_ZF + SZ_ZF)
#define OFF_TM   (OFF_MO + SZ_ZF)
#define OFF_WT   (OFF_TM + SZ_ZC)
#define OFF_TAB  (OFF_WT + SZ_WT)
#define OFF_STAT (OFF_TAB + SZ_TAB)
// total = OFF_STAT + 512 = 58,545,536 floats = 223.3 MiB  (fits 256 MiB ws)
// setup-only scratch aliases the G region (overwritten later by k_gfill):
#define A_XIN  OFF_G                   // B*32*HW
#define A_XI0  (OFF_G + SZ_T)         // B*16*HW

// stats sublayout (floats within STAT region)
#define ST_GN1   0     // 16
#define ST_GN2   16    // 16
#define ST_INJ   32    // 16
#define ST_BN    48    // 64
#define ST_GRAM  112   // 60  (4 batches x 15 packed lower-tri)
#define ST_ALPHA 172   // 20

// ---------------- small utility kernels ----------------
__global__ void k_zero(float* p, int n) {
    int i = blockIdx.x * blockDim.x + threadIdx.x;
    if (i < n) p[i] = 0.f;
}

__global__ void k_tables(float* tab) {
    int i = blockIdx.x * blockDim.x + threadIdx.x;  // 13*192
    if (i < 13 * 192) {
        int k = i / 192, x = i % 192;
        double th = 2.0 * M_PI * (double)(k * x) / 192.0;
        tab[i] = (float)cos(th);
        tab[13 * 192 + i] = (float)sin(th);
    }
}

// transpose spectral weights to wt[j][ky][i][o][2], j in 0..23
__global__ void k_wt(const float* __restrict__ w1r, const float* __restrict__ w1i,
                     const float* __restrict__ w2r, const float* __restrict__ w2i,
                     float* __restrict__ wt) {
    int idx = blockIdx.x * 256 + threadIdx.x;  // 24*12*32*32
    if (idx >= 24 * 12 * 1024) return;
    int o = idx & 31;
    int i = (idx >> 5) & 31;
    int ky = (idx >> 10) % 12;
    int j = idx / (12 * 1024);
    const float* wr;
    const float* wi;
    int x;
    if (j < 12) { wr = w1r; wi = w1i; x = j; }
    else        { wr = w2r; wi = w2i; x = j - 12; }
    int src = ((i * 32 + o) * 12 + x) * 12 + ky;
    size_t dst = (((size_t)j * 12 + ky) * 1024 + i * 32 + o) * 2;
    wt[dst] = wr[src];
    wt[dst + 1] = wi[src];
}

__global__ void k_fc0(const float* __restrict__ x, const float* __restrict__ w,
                      const float* __restrict__ bb, float* __restrict__ xin) {
    int i = blockIdx.x * 256 + threadIdx.x;
    if (i >= (int)SZ_T) return;
    int hw = i % HWc;
    int c = (i / HWc) % CCc;
    int b = i / (CCc * HWc);
    xin[i] = x[b * HWc + hw] * w[c] + bb[c];
}

// conv3x3 SAME, 32->16, block per (b,h), 192 threads, 2 channel passes
__global__ __launch_bounds__(192) void k_conv(const float* __restrict__ xin,
                                              const float* __restrict__ cw,
                                              float* __restrict__ xi0) {
    int b = blockIdx.x / HHc, h = blockIdx.x % HHc;
    __shared__ float sm[3 * 16 * WWc];
    int w = threadIdx.x;
    float acc[16];
#pragma unroll
    for (int n = 0; n < 16; ++n) acc[n] = 0.f;
    for (int cp = 0; cp < 2; ++cp) {
        __syncthreads();
        for (int i = threadIdx.x; i < 3 * 16 * WWc; i += 192) {
            int ww2 = i % WWc;
            int c16 = (i / WWc) % 16;
            int r = i / (WWc * 16);
            int h2 = h + r - 1;
            float v = 0.f;
            if (h2 >= 0 && h2 < HHc)
                v = xin[((size_t)b * CCc + cp * 16 + c16) * HWc + (size_t)h2 * WWc + ww2];
            sm[(r * 16 + c16) * WWc + ww2] = v;
        }
        __syncthreads();
        for (int c16 = 0; c16 < 16; ++c16) {
            const float* r0 = sm + (0 * 16 + c16) * WWc;
            const float* r1 = sm + (1 * 16 + c16) * WWc;
            const float* r2 = sm + (2 * 16 + c16) * WWc;
            float v0 = (w > 0) ? r0[w - 1] : 0.f, v1 = r0[w], v2 = (w < WWc - 1) ? r0[w + 1] : 0.f;
            float v3 = (w > 0) ? r1[w - 1] : 0.f, v4 = r1[w], v5 = (w < WWc - 1) ? r1[w + 1] : 0.f;
            float v6 = (w > 0) ? r2[w - 1] : 0.f, v7 = r2[w], v8 = (w < WWc - 1) ? r2[w + 1] : 0.f;
#pragma unroll
            for (int n = 0; n < 16; ++n) {
                const float* kw = cw + ((n * CCc + cp * 16 + c16) * 9);
                acc[n] += v0 * kw[0] + v1 * kw[1] + v2 * kw[2] + v3 * kw[3] + v4 * kw[4] +
                          v5 * kw[5] + v6 * kw[6] + v7 * kw[7] + v8 * kw[8];
            }
        }
    }
#pragma unroll
    for (int n = 0; n < 16; ++n)
        xi0[((size_t)b * NRk + n) * HWc + (size_t)h * WWc + w] = acc[n];
}

// generic contiguous-bin sum/sumsq with atomics
__global__ void k_binstats(const float* __restrict__ src, float* __restrict__ stats,
                           int binsize, int blocksPerBin) {
    int bin = blockIdx.x / blocksPerBin, sub = blockIdx.x % blocksPerBin;
    const float* p = src + (size_t)bin * binsize;
    float s = 0.f, q = 0.f;
    for (int i = sub * blockDim.x + threadIdx.x; i < binsize; i += blocksPerBin * blockDim.x) {
        float v = p[i];
        s += v;
        q += v * v;
    }
    for (int o = 32; o; o >>= 1) { s += __shfl_down(s, o); q += __shfl_down(q, o); }
    __shared__ float rs[4], rq[4];
    int wid = threadIdx.x >> 6, lane = threadIdx.x & 63;
    if (lane == 0) { rs[wid] = s; rq[wid] = q; }
    __syncthreads();
    if (threadIdx.x == 0) {
        int nw = blockDim.x >> 6;
        float ts = 0.f, tq = 0.f;
        for (int i = 0; i < nw; ++i) { ts += rs[i]; tq += rq[i]; }
        atomicAdd(&stats[bin * 2], ts);
        atomicAdd(&stats[bin * 2 + 1], tq);
    }
}

// xi = sigmoid(q_w * GN(xi0) + q_b), block per (b,h)
__global__ __launch_bounds__(192) void k_xi(const float* __restrict__ xi0,
                                            const float* __restrict__ stats,
                                            const float* __restrict__ gnw, const float* __restrict__ gnb,
                                            const float* __restrict__ qw, const float* __restrict__ qb,
                                            float* __restrict__ xi) {
    int b = blockIdx.x / HHc, h = blockIdx.x % HHc;
    __shared__ float t[16 * WWc];
    const float Ninv = 1.f / (8.f * HWc);
    for (int i = threadIdx.x; i < 16 * WWc; i += 192) {
        int w = i % WWc, n = i / WWc;
        int g = n >> 3;
        float su = stats[(b * 2 + g) * 2], sq = stats[(b * 2 + g) * 2 + 1];
        float mu = su * Ninv;
        float var = sq * Ninv - mu * mu;
        float inv = rsqrtf(var + EPSc);
        float v = xi0[((size_t)b * NRk + n) * HWc + (size_t)h * WWc + w];
        t[n * WWc + w] = (v - mu) * inv * gnw[n] + gnb[n];
    }
    __syncthreads();
    int w = threadIdx.x;
    for (int d = 0; d < 32; ++d) {
        float acc = qb[d];
#pragma unroll
        for (int n = 0; n < 16; ++n) acc += t[n * WWc + w] * qw[d * 16 + n];
        xi[((size_t)b * CCc + d) * HWc + (size_t)h * WWc + w] = 1.f / (1.f + expf(-acc));
    }
}

// ---------------- f_block kernels (z input: [b][D], batch stride D) ----------------
// forward DFT along W: z -> Zc[b,c,h,ky]{re,im}, ky 0..11
__global__ __launch_bounds__(192) void k_dftw(const float* __restrict__ z0,
                                              const float* __restrict__ tab,
                                              float* __restrict__ Zc) {
    int bc = blockIdx.x / 24;
    int hg = blockIdx.x % 24;
    int b = bc >> 5, c = bc & 31;
    const float* zp = z0 + (size_t)b * DDs + (size_t)c * HWc + (size_t)hg * 8 * WWc;
    __shared__ float rows[8 * 193];
    __shared__ float tb[24 * 193];
    for (int i = threadIdx.x; i < 8 * WWc; i += 192)
        rows[(i / WWc) * 193 + (i % WWc)] = zp[i];
    for (int i = threadIdx.x; i < 24 * WWc; i += 192) {
        int rr = i / WWc, col = i % WWc;
        tb[rr * 193 + col] = (rr < 12) ? tab[rr * 192 + col] : tab[2496 + (rr - 12) * 192 + col];
    }
    __syncthreads();
    int t = threadIdx.x;
    int r = t / 24, q = t % 24, ky = q >> 1, isim = q & 1;
    const float* tbp = tb + (isim ? (12 + ky) * 193 : ky * 193);
    const float* rowp = rows + r * 193;
    float acc = 0.f;
#pragma unroll 8
    for (int w2 = 0; w2 < WWc; ++w2) acc += rowp[w2] * tbp[w2];
    if (isim) acc = -acc;
    int h = hg * 8 + r;
    Zc[(((size_t)bc * HHc + h) * M1c + ky) * 2 + isim] = acc;
}

// forward DFT along H (24 freqs): Zc -> ZF[b,c,j,ky]{re,im}
__global__ __launch_bounds__(256) void k_dfth(const float* __restrict__ Zc,
                                              const float* __restrict__ tab,
                                              float* __restrict__ ZF) {
    int bc = blockIdx.x;
    __shared__ float zp[HHc * 12 * 2];
    const float* src = Zc + (size_t)bc * HHc * 12 * 2;
    for (int i = threadIdx.x; i < HHc * 12 * 2; i += 256) zp[i] = src[i];
    __syncthreads();
    const float* tc = tab;
    const float* ts = tab + 2496;
    for (int oidx = threadIdx.x; oidx < 288; oidx += 256) {
        int j = oidx / 12, ky = oidx % 12;
        int k = (j < 12) ? j : 24 - j;
        float sgn = (j < 12) ? 1.f : -1.f;
        float re = 0.f, im = 0.f;
        for (int h = 0; h < HHc; ++h) {
            float zr = zp[(h * 12 + ky) * 2], zi = zp[(h * 12 + ky) * 2 + 1];
            float cv = tc[k * 192 + h], sv = sgn * ts[k * 192 + h];
            re += zr * cv + zi * sv;
            im += zi * cv - zr * sv;
        }
        ZF[((size_t)bc * 288 + oidx) * 2] = re;
        ZF[((size_t)bc * 288 + oidx) * 2 + 1] = im;
    }
}

// mode mixing: MO[b,o,mode] = sum_i ZF[b,i,mode]*wt[mode][i][o]
__global__ __launch_bounds__(64) void k_mix(const float* __restrict__ ZF,
                                            const float* __restrict__ wt,
                                            float* __restrict__ MO) {
    int b = blockIdx.x / 288, mode = blockIdx.x % 288;
    __shared__ float zin[64];
    int t = threadIdx.x;
    zin[t] = ZF[(((size_t)b * 32 + (t >> 1)) * 288 + mode) * 2 + (t & 1)];
    __syncthreads();
    int o = t >> 1, ri = t & 1;
    const float* wp = wt + (size_t)mode * 2048;
    float acc = 0.f;
#pragma unroll 8
    for (int i = 0; i < 32; ++i) {
        float ar = zin[2 * i], ai = zin[2 * i + 1];
        float wr = wp[(i * 32 + o) * 2], wi = wp[(i * 32 + o) * 2 + 1];
        acc += ri ? (ar * wi + ai * wr) : (ar * wr - ai * wi);
    }
    MO[(((size_t)b * 32 + o) * 288 + mode) * 2 + ri] = acc;
}

// inverse DFT along H: MO -> Tm[b,o,h,ky]{re,im}, scaled 1/H; also zeroes gn stats
__global__ __launch_bounds__(256) void k_idfth(const float* __restrict__ MO,
                                               const float* __restrict__ tab,
                                               float* __restrict__ Tm,
                                               float* __restrict__ gnstats) {
    if (blockIdx.x == 0 && threadIdx.x < 32) gnstats[threadIdx.x] = 0.f;
    int bo = blockIdx.x;
    __shared__ float mp[576];
    const float* src = MO + (size_t)bo * 576;
    for (int i = threadIdx.x; i < 576; i += 256) mp[i] = src[i];
    __syncthreads();
    const float* tc = tab;
    const float* ts = tab + 2496;
    const float scale = 1.f / 192.f;
    for (int oidx = threadIdx.x; oidx < HHc * 12; oidx += 256) {
        int h = oidx / 12, ky = oidx % 12;
        float re = 0.f, im = 0.f;
#pragma unroll
        for (int j = 0; j < 24; ++j) {
            int k = (j < 12) ? j : 24 - j;
            float sgn = (j < 12) ? 1.f : -1.f;
            float mr = mp[(j * 12 + ky) * 2], mi = mp[(j * 12 + ky) * 2 + 1];
            float cv = tc[k * 192 + h], sv = sgn * ts[k * 192 + h];
            re += mr * cv - mi * sv;
            im += mr * sv + mi * cv;
        }
        Tm[((size_t)bo * HHc + h) * 24 + ky * 2] = re * scale;
        Tm[((size_t)bo * HHc + h) * 24 + ky * 2 + 1] = im * scale;
    }
}

// inverse DFT along W + y2(1x1 conv) + exact gelu + xi add -> sbuf (= dest F slot);
// gn1 stat accumulate
__global__ __launch_bounds__(192) void k_f5(const float* __restrict__ z0,
                                            const float* __restrict__ Tm,
                                            const float* __restrict__ xi,
                                            const float* __restrict__ w0w,
                                            const float* __restrict__ w0b,
                                            const float* __restrict__ tab,
                                            float* __restrict__ sbuf,
                                            float* __restrict__ gn1) {
    int b = blockIdx.x / HHc, h = blockIdx.x % HHc;
    __shared__ float zt[32 * WWc];
    __shared__ float w0s[1024];
    __shared__ float tms[32 * 24];
    __shared__ float red[3][4];
    const float* zp = z0 + (size_t)b * DDs + (size_t)h * WWc;
#pragma unroll 4
    for (int c = 0; c < 32; ++c) zt[c * WWc + threadIdx.x] = zp[(size_t)c * HWc + threadIdx.x];
    for (int i = threadIdx.x; i < 1024; i += 192) w0s[i] = w0w[i];
    for (int i = threadIdx.x; i < 32 * 24; i += 192) {
        int o = i / 24, u = i % 24;
        tms[i] = Tm[(((size_t)b * 32 + o) * HHc + h) * 24 + u];
    }
    __syncthreads();
    int w = threadIdx.x;
    float cwv[11], swv[11];
#pragma unroll
    for (int ky = 1; ky <= 11; ++ky) {
        cwv[ky - 1] = tab[ky * 192 + w];
        swv[ky - 1] = tab[2496 + ky * 192 + w];
    }
    float s0 = 0.f, q0 = 0.f, s1 = 0.f, q1 = 0.f;
    const float Winv = 1.f / 192.f;
    for (int o = 0; o < 32; ++o) {
        const float* tm = tms + o * 24;
        float y1 = tm[0];
#pragma unroll
        for (int ky = 1; ky <= 11; ++ky)
            y1 += 2.f * (tm[2 * ky] * cwv[ky - 1] - tm[2 * ky + 1] * swv[ky - 1]);
        y1 *= Winv;
        float y2 = w0b[o];
#pragma unroll 8
        for (int c = 0; c < 32; ++c) y2 += zt[c * WWc + w] * w0s[o * 32 + c];
        float v = y1 + y2;
        float u = 0.5f * v * (1.f + erff(v * 0.70710678118654752f));
        size_t gi = (size_t)b * DDs + (size_t)o * HWc + (size_t)h * WWc + w;
        float sv = xi[gi] + u;
        sbuf[gi] = sv;
        if (o < 16) { s0 += sv; q0 += sv * sv; }
        else        { s1 += sv; q1 += sv * sv; }
    }
    for (int o = 32; o; o >>= 1) {
        s0 += __shfl_down(s0, o); q0 += __shfl_down(q0, o);
        s1 += __shfl_down(s1, o); q1 += __shfl_down(q1, o);
    }
    int wid = threadIdx.x >> 6, lane = threadIdx.x & 63;
    if (lane == 0) { red[wid][0] = s0; red[wid][1] = q0; red[wid][2] = s1; red[wid][3] = q1; }
    __syncthreads();
    if (threadIdx.x == 0) {
        float a0 = 0, a1 = 0, a2 = 0, a3 = 0;
        for (int i = 0; i < 3; ++i) { a0 += red[i][0]; a1 += red[i][1]; a2 += red[i][2]; a3 += red[i][3]; }
        atomicAdd(&gn1[(b * 2 + 0) * 2], a0);
        atomicAdd(&gn1[(b * 2 + 0) * 2 + 1], a1);
        atomicAdd(&gn1[(b * 2 + 1) * 2], a2);
        atomicAdd(&gn1[(b * 2 + 1) * 2 + 1], a3);
    }
}

// buf = relu(z + GN1(buf)) IN PLACE; accumulate gn2 stats
__global__ __launch_bounds__(256) void k_f6(const float* __restrict__ z0,
                                            float* buf,
                                            const float* __restrict__ gn1,
                                            const float* __restrict__ n1w,
                                            const float* __restrict__ n1b,
                                            float* __restrict__ gn2) {
    const int binsize = 16 * HWc;
    const int BPB = 32;
    int bin = blockIdx.x / BPB, sub = blockIdx.x % BPB;
    int b = bin >> 1;
    float Nv = (float)binsize;
    float su = gn1[bin * 2], sq = gn1[bin * 2 + 1];
    float mu = su / Nv;
    float var = sq / Nv - mu * mu;
    float inv = rsqrtf(var + EPSc);
    size_t base = (size_t)bin * binsize;
    const float* zb = z0 + (size_t)b * DDs;
    float s = 0.f, q = 0.f;
    for (int i = sub * 256 + threadIdx.x; i < binsize; i += BPB * 256) {
        size_t e = base + i;
        size_t loc = e - (size_t)b * DDs;
        int c = (int)(loc / HWc);
        float sv = buf[e];
        float t = (sv - mu) * inv * n1w[c] + n1b[c];
        float r = zb[loc] + t;
        r = r > 0.f ? r : 0.f;
        buf[e] = r;
        s += r;
        q += r * r;
    }
    for (int o = 32; o; o >>= 1) { s += __shfl_down(s, o); q += __shfl_down(q, o); }
    __shared__ float rs[4], rq[4];
    int wid = threadIdx.x >> 6, lane = threadIdx.x & 63;
    if (lane == 0) { rs[wid] = s; rq[wid] = q; }
    __syncthreads();
    if (threadIdx.x == 0) {
        float ts = rs[0] + rs[1] + rs[2] + rs[3];
        float tq = rq[0] + rq[1] + rq[2] + rq[3];
        atomicAdd(&gn2[bin * 2], ts);
        atomicAdd(&gn2[bin * 2 + 1], tq);
    }
}

// buf = GN2(buf) IN PLACE
__global__ __launch_bounds__(256) void k_f7(float* buf,
                                            const float* __restrict__ gn2,
                                            const float* __restrict__ n2w,
                                            const float* __restrict__ n2b) {
    int e = blockIdx.x * 256 + threadIdx.x;
    if (e >= (int)SZ_T) return;
    int b = e / DDi;
    int loc = e % DDi;
    int c = loc / HWc;
    int bin = b * 2 + (c >> 4);
    const float Ninv = 1.f / (16.f * HWc);
    float su = gn2[bin * 2], sq = gn2[bin * 2 + 1];
    float mu = su * Ninv;
    float var = sq * Ninv - mu * mu;
    float inv = rsqrtf(var + EPSc);
    buf[e] = (buf[e] - mu) * inv * n2w[c] + n2b[c];
}

// G_slot = F_slot - zin  (elementwise, flat B*D)
__global__ void k_gfill(const float* __restrict__ Fs, const float* __restrict__ zin,
                        float* __restrict__ Gs) {
    int i = blockIdx.x * 256 + threadIdx.x;
    if (i >= (int)SZ_T) return;
    Gs[i] = Fs[i] - zin[i];
}

// ---------------- Anderson kernels ----------------
// Gram of G slots: gram[b][15] packed lower-tri, G layout [slot][B][D]
__global__ __launch_bounds__(256) void k_gram(const float* __restrict__ G,
                                              float* __restrict__ gram) {
    const int NB = 36;
    int b = blockIdx.x / NB, sub = blockIdx.x % NB;
    const float* gb = G + (size_t)b * DDs;
    const size_t SS = SZ_T;
    float a00 = 0, a10 = 0, a11 = 0, a20 = 0, a21 = 0, a22 = 0, a30 = 0, a31 = 0,
          a32 = 0, a33 = 0, a40 = 0, a41 = 0, a42 = 0, a43 = 0, a44 = 0;
    for (int e = sub * 256 + threadIdx.x; e < DDi; e += NB * 256) {
        float g0 = gb[e];
        float g1 = gb[SS + e];
        float g2 = gb[2 * SS + e];
        float g3 = gb[3 * SS + e];
        float g4 = gb[4 * SS + e];
        a00 += g0 * g0; a10 += g1 * g0; a11 += g1 * g1;
        a20 += g2 * g0; a21 += g2 * g1; a22 += g2 * g2;
        a30 += g3 * g0; a31 += g3 * g1; a32 += g3 * g2; a33 += g3 * g3;
        a40 += g4 * g0; a41 += g4 * g1; a42 += g4 * g2; a43 += g4 * g3; a44 += g4 * g4;
    }
    float acc[15] = {a00, a10, a11, a20, a21, a22, a30, a31, a32, a33, a40, a41, a42, a43, a44};
    __shared__ float red[4][15];
    int wid = threadIdx.x >> 6, lane = threadIdx.x & 63;
#pragma unroll
    for (int p = 0; p < 15; ++p) {
        float v = acc[p];
        for (int o = 32; o; o >>= 1) v += __shfl_down(v, o);
        if (lane == 0) red[wid][p] = v;
    }
    __syncthreads();
    if (threadIdx.x == 0) {
#pragma unroll
        for (int p = 0; p < 15; ++p)
            atomicAdd(&gram[b * 15 + p], red[0][p] + red[1][p] + red[2][p] + red[3][p]);
    }
}

__global__ void k_solve(float* __restrict__ gram, float* __restrict__ alpha, int n) {
    int b = threadIdx.x;
    if (b >= BBc) return;
    float A[6][7];
    int nn = n + 1;
    for (int i = 0; i < nn; ++i)
        for (int j = 0; j <= nn; ++j) A[i][j] = 0.f;
    for (int j = 1; j < nn; ++j) { A[0][j] = 1.f; A[j][0] = 1.f; }
    for (int i = 0; i < n; ++i)
        for (int j = 0; j < n; ++j) {
            int ii = i > j ? i : j, jj = i > j ? j : i;
            float v = gram[b * 15 + ii * (ii + 1) / 2 + jj];
            A[i + 1][j + 1] = v + ((i == j) ? 1e-4f : 0.f);
        }
    A[0][nn] = 1.f;
    for (int col = 0; col < nn; ++col) {
        int piv = col;
        float best = fabsf(A[col][col]);
        for (int r2 = col + 1; r2 < nn; ++r2) {
            float av = fabsf(A[r2][col]);
            if (av > best) { best = av; piv = r2; }
        }
        if (piv != col)
            for (int c2 = 0; c2 <= nn; ++c2) {
                float tv = A[col][c2];
                A[col][c2] = A[piv][c2];
                A[piv][c2] = tv;
            }
        float d = A[col][col];
        for (int r2 = col + 1; r2 < nn; ++r2) {
            float f = A[r2][col] / d;
            for (int c2 = col; c2 <= nn; ++c2) A[r2][c2] -= f * A[col][c2];
        }
    }
    float sol[6];
    for (int r2 = nn - 1; r2 >= 0; --r2) {
        float v = A[r2][nn];
        for (int c2 = r2 + 1; c2 < nn; ++c2) v -= A[r2][c2] * sol[c2];
        sol[r2] = v / A[r2][r2];
    }
    for (int j = 0; j < 5; ++j) alpha[b * 5 + j] = (j < n) ? sol[j + 1] : 0.f;
    for (int p = 0; p < 15; ++p) gram[b * 15 + p] = 0.f;
}

// xcur = sum_j alpha_j * F[j]   (F layout [slot][B][D], flat i = b*D+loc)
__global__ void k_xnew(const float* __restrict__ F, const float* __restrict__ alpha,
                       float* __restrict__ xcur) {
    int i = blockIdx.x * 256 + threadIdx.x;
    if (i >= (int)SZ_T) return;
    int b = i / DDi;
    const size_t SS = SZ_T;
    float a0 = alpha[b * 5], a1 = alpha[b * 5 + 1], a2 = alpha[b * 5 + 2];
    float a3 = alpha[b * 5 + 3], a4 = alpha[b * 5 + 4];
    xcur[i] = a0 * F[i] + a1 * F[SS + i] + a2 * F[2 * SS + i] +
              a3 * F[3 * SS + i] + a4 * F[4 * SS + i];
}

// ---------------- final: BN stats + BN + fc1(gelu) + fc2 ----------------
__global__ __launch_bounds__(256) void k_bnstats(const float* __restrict__ z,
                                                 float* __restrict__ bstats) {
    const int BPB = 18;
    int c = blockIdx.x / BPB, sub = blockIdx.x % BPB;
    float s = 0.f, q = 0.f;
    for (int i = sub * 256 + threadIdx.x; i < BBc * HWc; i += BPB * 256) {
        int b = i / HWc, hw = i % HWc;
        float v = z[(size_t)b * DDs + (size_t)c * HWc + hw];
        s += v;
        q += v * v;
    }
    for (int o = 32; o; o >>= 1) { s += __shfl_down(s, o); q += __shfl_down(q, o); }
    __shared__ float rs[4], rq[4];
    int wid = threadIdx.x >> 6, lane = threadIdx.x & 63;
    if (lane == 0) { rs[wid] = s; rq[wid] = q; }
    __syncthreads();
    if (threadIdx.x == 0) {
        atomicAdd(&bstats[c * 2], rs[0] + rs[1] + rs[2] + rs[3]);
        atomicAdd(&bstats[c * 2 + 1], rq[0] + rq[1] + rq[2] + rq[3]);
    }
}

__global__ __launch_bounds__(192) void k_final(const float* __restrict__ z,
                                               const float* __restrict__ bstats,
                                               const float* __restrict__ bnw,
                                               const float* __restrict__ bnb,
                                               const float* __restrict__ fc1w,
                                               const float* __restrict__ fc1b,
                                               const float* __restrict__ fc2w,
                                               const float* __restrict__ fc2b,
                                               float* __restrict__ out) {
    int b = blockIdx.x / HHc, h = blockIdx.x % HHc;
    __shared__ float zb[32 * WWc];
    const float Ninv = 1.f / ((float)BBc * HWc);
    for (int c = 0; c < 32; ++c) {
        float su = bstats[c * 2], sq = bstats[c * 2 + 1];
        float mu = su * Ninv;
        float var = sq * Ninv - mu * mu;
        float inv = rsqrtf(var + EPSc);
        float v = z[(size_t)b * DDs + (size_t)c * HWc + (size_t)h * WWc + threadIdx.x];
        zb[c * WWc + threadIdx.x] = (v - mu) * inv * bnw[c] + bnb[c];
    }
    __syncthreads();
    int w = threadIdx.x;
    float acc2 = fc2b[0];
    for (int o = 0; o < 32; ++o) {
        float a = fc1b[o];
#pragma unroll 8
        for (int c = 0; c < 32; ++c) a += zb[c * WWc + w] * fc1w[o * 32 + c];
        float g = 0.5f * a * (1.f + erff(a * 0.70710678118654752f));
        acc2 += fc2w[o] * g;
    }
    out[(size_t)b * HWc + (size_t)h * WWc + w] = acc2;
}

// ---------------- host ----------------
extern "C" void kernel_launch(void* const* d_in, const int* in_sizes, int n_in,
                              void* d_out, int out_size, void* d_ws, size_t ws_size,
                              hipStream_t stream) {
    (void)in_sizes; (void)n_in; (void)out_size; (void)ws_size;
    const float* x    = (const float*)d_in[0];
    const float* fc0w = (const float*)d_in[1];
    const float* fc0b = (const float*)d_in[2];
    const float* convw = (const float*)d_in[3];
    const float* gnw  = (const float*)d_in[4];
    const float* gnb  = (const float*)d_in[5];
    const float* qw   = (const float*)d_in[6];
    const float* qb   = (const float*)d_in[7];
    const float* sw1r = (const float*)d_in[8];
    const float* sw1i = (const float*)d_in[9];
    const float* sw2r = (const float*)d_in[10];
    const float* sw2i = (const float*)d_in[11];
    const float* w0w  = (const float*)d_in[12];
    const float* w0b  = (const float*)d_in[13];
    const float* n1w  = (const float*)d_in[14];
    const float* n1b  = (const float*)d_in[15];
    const float* n2w  = (const float*)d_in[16];
    const float* n2b  = (const float*)d_in[17];
    const float* bnw  = (const float*)d_in[18];
    const float* bnb  = (const float*)d_in[19];
    const float* fc1w = (const float*)d_in[20];
    const float* fc1b = (const float*)d_in[21];
    const float* fc2w = (const float*)d_in[22];
    const float* fc2b = (const float*)d_in[23];
    float* out = (float*)d_out;

    float* ws = (float*)d_ws;
    float* XC  = ws + OFF_XC;
    float* XIp = ws + OFF_XI;
    float* Fb  = ws + OFF_F;
    float* Gb  = ws + OFF_G;
    float* ZC  = ws + OFF_ZC;
    float* ZFp = ws + OFF_ZF;
    float* MOp = ws + OFF_MO;
    float* TM  = ws + OFF_TM;
    float* WT  = ws + OFF_WT;
    float* TAB = ws + OFF_TAB;
    float* ST  = ws + OFF_STAT;
    float* XIN = ws + A_XIN;   // setup alias (inside G region)
    float* XI0 = ws + A_XI0;   // setup alias (inside G region)

    const int TBLK = (int)((SZ_T + 255) / 256);  // 18432

    // one f_block evaluation: reads z ([b][D], stride D), writes F slot outslot
    auto runf = [&](const float* zin, int outslot) {
        float* dst = Fb + (size_t)outslot * SZ_T;
        k_dftw<<<BBc * CCc * 24, 192, 0, stream>>>(zin, TAB, ZC);
        k_dfth<<<BBc * CCc, 256, 0, stream>>>(ZC, TAB, ZFp);
        k_mix<<<BBc * 288, 64, 0, stream>>>(ZFp, WT, MOp);
        k_idfth<<<BBc * CCc, 256, 0, stream>>>(MOp, TAB, TM, ST + ST_GN1);
        k_f5<<<BBc * HHc, 192, 0, stream>>>(zin, TM, XIp, w0w, w0b, TAB, dst, ST + ST_GN1);
        k_f6<<<8 * 32, 256, 0, stream>>>(zin, dst, ST + ST_GN1, n1w, n1b, ST + ST_GN2);
        k_f7<<<TBLK, 256, 0, stream>>>(dst, ST + ST_GN2, n2w, n2b);
    };

    // setup
    k_tables<<<10, 256, 0, stream>>>(TAB);
    k_wt<<<(24 * 12 * 1024 + 255) / 256, 256, 0, stream>>>(sw1r, sw1i, sw2r, sw2i, WT);
    k_zero<<<2, 256, 0, stream>>>(ST, 512);
    k_fc0<<<TBLK, 256, 0, stream>>>(x, fc0w, fc0b, XIN);
    k_conv<<<BBc * HHc, 192, 0, stream>>>(XIN, convw, XI0);
    k_binstats<<<8 * 36, 256, 0, stream>>>(XI0, ST + ST_INJ, 8 * HWc, 36);
    k_xi<<<BBc * HHc, 192, 0, stream>>>(XI0, ST + ST_INJ, gnw, gnb, qw, qb, XIp);
    k_zero<<<TBLK, 256, 0, stream>>>(XC, (int)SZ_T);

    // f0 = f(0) -> F0 ; G0 = F0 - 0
    runf(XC, 0);
    k_gfill<<<TBLK, 256, 0, stream>>>(Fb, XC, Gb);
    // f1 = f(F0) -> F1 ; G1 = F1 - F0
    runf(Fb, 1);
    k_gfill<<<TBLK, 256, 0, stream>>>(Fb + SZ_T, Fb, Gb + SZ_T);

    // Anderson iterations k = 2..15
    for (int k = 2; k < 16; ++k) {
        int n = k < 5 ? k : 5;
        int slot = k % 5;
        k_gram<<<BBc * 36, 256, 0, stream>>>(Gb, ST + ST_GRAM);
        k_solve<<<1, 64, 0, stream>>>(ST + ST_GRAM, ST + ST_ALPHA, n);
        k_xnew<<<TBLK, 256, 0, stream>>>(Fb, ST + ST_ALPHA, XC);
        runf(XC, slot);
        k_gfill<<<TBLK, 256, 0, stream>>>(Fb + (size_t)slot * SZ_T, XC,
                                          Gb + (size_t)slot * SZ_T);
    }

    // final z = F slot 0; BatchNorm + fc1(gelu) + fc2
    k_bnstats<<<32 * 18, 256, 0, stream>>>(Fb, ST + ST_BN);
    k_final<<<BBc * HHc, 192, 0, stream>>>(Fb, ST + ST_BN, bnw, bnb, fc1w, fc1b, fc2w, fc2b, out);
}

// Round 3
// 4097.900 us; speedup vs baseline: 1.1011x; 1.1011x over previous
//
#include <hip/hip_runtime.h>
#include <math.h>

#ifndef M_PI
#define M_PI 3.14159265358979323846
#endif

#define BBc 4
#define CCc 32
#define NRk 16
#define HHc 192
#define WWc 192
#define HWc 36864
#define DDi 1179648
#define M1c 12
#define EPSc 1e-5f

static const size_t DDs = (size_t)DDi;

// ---------------- workspace layout (floats) ----------------
#define SZ_T   ((size_t)4718592)       // B*C*HW  (= B*D)
#define SZ_ZC  ((size_t)589824)        // B*C*H*12*2
#define SZ_ZF  ((size_t)73728)         // B*C*24*12*2
#define SZ_WT  ((size_t)589824)        // 24*12*32*32*2
#define SZ_TAB ((size_t)4992)          // 13*192*2

#define OFF_XC   ((size_t)0)                  // xcur      (B*D)
#define OFF_XI   (OFF_XC + SZ_T)              // xi        (B*D)
#define OFF_F    (OFF_XI + SZ_T)              // F history [slot][B][D], 5 slots
#define OFF_G    (OFF_F + 5 * SZ_T)           // G history [slot][B][D], 5 slots
#define OFF_ZC   (OFF_G + 5 * SZ_T)
#define OFF_ZF   (OFF_ZC + SZ_ZC)
#define OFF_MO   (OFF_ZF + SZ_ZF)
#define OFF_TM   (OFF_MO + SZ_ZF)
#define OFF_WT   (OFF_TM + SZ_ZC)
#define OFF_TAB  (OFF_WT + SZ_WT)
#define OFF_STAT (OFF_TAB + SZ_TAB)
// total ~223.3 MiB (fits 256 MiB ws)
// setup-only scratch aliases the G region (G written later by k_f7g):
#define A_XI0  OFF_G                   // B*16*HW

// stats sublayout (floats within STAT region)
#define ST_GN1   0     // 16
#define ST_GN2   16    // 16
#define ST_INJ   32    // 16
#define ST_BN    48    // 64
#define ST_GRAM  112   // 60  (4 batches x 15 packed lower-tri, PERSISTENT)
#define ST_ALPHA 172   // 20

// ---------------- small utility kernels ----------------
__global__ void k_zero(float* p, int n) {
    int i = blockIdx.x * blockDim.x + threadIdx.x;
    if (i < n) p[i] = 0.f;
}

__global__ void k_tables(float* tab) {
    int i = blockIdx.x * blockDim.x + threadIdx.x;  // 13*192
    if (i < 13 * 192) {
        int k = i / 192, x = i % 192;
        double th = 2.0 * M_PI * (double)(k * x) / 192.0;
        tab[i] = (float)cos(th);
        tab[13 * 192 + i] = (float)sin(th);
    }
}

// transpose spectral weights to wt[j][ky][i][o][2], j in 0..23
__global__ void k_wt(const float* __restrict__ w1r, const float* __restrict__ w1i,
                     const float* __restrict__ w2r, const float* __restrict__ w2i,
                     float* __restrict__ wt) {
    int idx = blockIdx.x * 256 + threadIdx.x;  // 24*12*32*32
    if (idx >= 24 * 12 * 1024) return;
    int o = idx & 31;
    int i = (idx >> 5) & 31;
    int ky = (idx >> 10) % 12;
    int j = idx / (12 * 1024);
    const float* wr;
    const float* wi;
    int x;
    if (j < 12) { wr = w1r; wi = w1i; x = j; }
    else        { wr = w2r; wi = w2i; x = j - 12; }
    int src = ((i * 32 + o) * 12 + x) * 12 + ky;
    size_t dst = (((size_t)j * 12 + ky) * 1024 + i * 32 + o) * 2;
    wt[dst] = wr[src];
    wt[dst + 1] = wi[src];
}

// conv3x3 SAME, (fc0 fused) 1->32->16, block per (b,h), 192 threads
__global__ __launch_bounds__(192) void k_conv(const float* __restrict__ x,
                                              const float* __restrict__ fc0w,
                                              const float* __restrict__ fc0b,
                                              const float* __restrict__ cw,
                                              float* __restrict__ xi0) {
    int b = blockIdx.x / HHc, h = blockIdx.x % HHc;
    __shared__ float sm[3 * 16 * WWc];
    int w = threadIdx.x;
    float acc[16];
#pragma unroll
    for (int n = 0; n < 16; ++n) acc[n] = 0.f;
    for (int cp = 0; cp < 2; ++cp) {
        __syncthreads();
        for (int i = threadIdx.x; i < 3 * 16 * WWc; i += 192) {
            int ww2 = i % WWc;
            int c16 = (i / WWc) % 16;
            int r = i / (WWc * 16);
            int h2 = h + r - 1;
            float v = 0.f;
            if (h2 >= 0 && h2 < HHc) {
                int cc = cp * 16 + c16;
                float xv = x[(size_t)b * HWc + (size_t)h2 * WWc + ww2];
                v = xv * fc0w[cc] + fc0b[cc];
            }
            sm[(r * 16 + c16) * WWc + ww2] = v;
        }
        __syncthreads();
        for (int c16 = 0; c16 < 16; ++c16) {
            const float* r0 = sm + (0 * 16 + c16) * WWc;
            const float* r1 = sm + (1 * 16 + c16) * WWc;
            const float* r2 = sm + (2 * 16 + c16) * WWc;
            float v0 = (w > 0) ? r0[w - 1] : 0.f, v1 = r0[w], v2 = (w < WWc - 1) ? r0[w + 1] : 0.f;
            float v3 = (w > 0) ? r1[w - 1] : 0.f, v4 = r1[w], v5 = (w < WWc - 1) ? r1[w + 1] : 0.f;
            float v6 = (w > 0) ? r2[w - 1] : 0.f, v7 = r2[w], v8 = (w < WWc - 1) ? r2[w + 1] : 0.f;
#pragma unroll
            for (int n = 0; n < 16; ++n) {
                const float* kw = cw + ((n * CCc + cp * 16 + c16) * 9);
                acc[n] += v0 * kw[0] + v1 * kw[1] + v2 * kw[2] + v3 * kw[3] + v4 * kw[4] +
                          v5 * kw[5] + v6 * kw[6] + v7 * kw[7] + v8 * kw[8];
            }
        }
    }
#pragma unroll
    for (int n = 0; n < 16; ++n)
        xi0[((size_t)b * NRk + n) * HWc + (size_t)h * WWc + w] = acc[n];
}

// generic contiguous-bin sum/sumsq with atomics
__global__ void k_binstats(const float* __restrict__ src, float* __restrict__ stats,
                           int binsize, int blocksPerBin) {
    int bin = blockIdx.x / blocksPerBin, sub = blockIdx.x % blocksPerBin;
    const float* p = src + (size_t)bin * binsize;
    float s = 0.f, q = 0.f;
    for (int i = sub * blockDim.x + threadIdx.x; i < binsize; i += blocksPerBin * blockDim.x) {
        float v = p[i];
        s += v;
        q += v * v;
    }
    for (int o = 32; o; o >>= 1) { s += __shfl_down(s, o); q += __shfl_down(q, o); }
    __shared__ float rs[4], rq[4];
    int wid = threadIdx.x >> 6, lane = threadIdx.x & 63;
    if (lane == 0) { rs[wid] = s; rq[wid] = q; }
    __syncthreads();
    if (threadIdx.x == 0) {
        int nw = blockDim.x >> 6;
        float ts = 0.f, tq = 0.f;
        for (int i = 0; i < nw; ++i) { ts += rs[i]; tq += rq[i]; }
        atomicAdd(&stats[bin * 2], ts);
        atomicAdd(&stats[bin * 2 + 1], tq);
    }
}

// xi = sigmoid(q_w * GN(xi0) + q_b), block per (b,h), register-blocked
__global__ __launch_bounds__(192) void k_xi(const float* __restrict__ xi0,
                                            const float* __restrict__ stats,
                                            const float* __restrict__ gnw, const float* __restrict__ gnb,
                                            const float* __restrict__ qw, const float* __restrict__ qb,
                                            float* __restrict__ xi) {
    int b = blockIdx.x / HHc, h = blockIdx.x % HHc;
    int w = threadIdx.x;
    const float Ninv = 1.f / (8.f * HWc);
    float tn[16];
#pragma unroll
    for (int n = 0; n < 16; ++n) {
        int g = n >> 3;
        float su = stats[(b * 2 + g) * 2], sq = stats[(b * 2 + g) * 2 + 1];
        float mu = su * Ninv;
        float var = sq * Ninv - mu * mu;
        float inv = rsqrtf(var + EPSc);
        float v = xi0[((size_t)b * NRk + n) * HWc + (size_t)h * WWc + w];
        tn[n] = (v - mu) * inv * gnw[n] + gnb[n];
    }
#pragma unroll
    for (int d = 0; d < 32; ++d) {
        float acc = qb[d];
        const float* row = qw + d * 16;
#pragma unroll
        for (int n = 0; n < 16; ++n) acc += tn[n] * row[n];
        xi[((size_t)b * CCc + d) * HWc + (size_t)h * WWc + w] = 1.f / (1.f + expf(-acc));
    }
}

// ---------------- f_block kernels (z input: [b][D], batch stride D) ----------------
// forward DFT along W: z -> Zc[b,c,h,ky]{re,im}, ky 0..11
__global__ __launch_bounds__(192) void k_dftw(const float* __restrict__ z0,
                                              const float* __restrict__ tab,
                                              float* __restrict__ Zc) {
    int bc = blockIdx.x / 24;
    int hg = blockIdx.x % 24;
    int b = bc >> 5, c = bc & 31;
    const float* zp = z0 + (size_t)b * DDs + (size_t)c * HWc + (size_t)hg * 8 * WWc;
    __shared__ float rows[8 * 196];
    __shared__ float tb[24 * 196];
    for (int i = threadIdx.x; i < 8 * WWc; i += 192)
        rows[(i / WWc) * 196 + (i % WWc)] = zp[i];
    for (int i = threadIdx.x; i < 24 * WWc; i += 192) {
        int rr = i / WWc, col = i % WWc;
        tb[rr * 196 + col] = (rr < 12) ? tab[rr * 192 + col] : tab[2496 + (rr - 12) * 192 + col];
    }
    __syncthreads();
    int t = threadIdx.x;
    int r = t / 24, q = t % 24, ky = q >> 1, isim = q & 1;
    const float* tbp = tb + (isim ? (12 + ky) * 196 : ky * 196);
    const float* rowp = rows + r * 196;
    float a0 = 0.f, a1 = 0.f, a2 = 0.f, a3 = 0.f;
#pragma unroll
    for (int w2 = 0; w2 < WWc; w2 += 4) {
        a0 += rowp[w2] * tbp[w2];
        a1 += rowp[w2 + 1] * tbp[w2 + 1];
        a2 += rowp[w2 + 2] * tbp[w2 + 2];
        a3 += rowp[w2 + 3] * tbp[w2 + 3];
    }
    float acc = (a0 + a1) + (a2 + a3);
    if (isim) acc = -acc;
    int h = hg * 8 + r;
    Zc[(((size_t)bc * HHc + h) * M1c + ky) * 2 + isim] = acc;
}

// forward DFT along H (24 freqs): Zc -> ZF[b,c,j,ky]{re,im}
__global__ __launch_bounds__(256) void k_dfth(const float* __restrict__ Zc,
                                              const float* __restrict__ tab,
                                              float* __restrict__ ZF) {
    int bc = blockIdx.x;
    __shared__ float zp[HHc * 12 * 2];
    const float* src = Zc + (size_t)bc * HHc * 12 * 2;
    for (int i = threadIdx.x; i < HHc * 12 * 2; i += 256) zp[i] = src[i];
    __syncthreads();
    const float* tc = tab;
    const float* ts = tab + 2496;
    for (int oidx = threadIdx.x; oidx < 288; oidx += 256) {
        int j = oidx / 12, ky = oidx % 12;
        int k = (j < 12) ? j : 24 - j;
        float sgn = (j < 12) ? 1.f : -1.f;
        float re0 = 0.f, im0 = 0.f, re1 = 0.f, im1 = 0.f;
        for (int h = 0; h < HHc; h += 2) {
            float zr = zp[(h * 12 + ky) * 2], zi = zp[(h * 12 + ky) * 2 + 1];
            float cv = tc[k * 192 + h], sv = sgn * ts[k * 192 + h];
            re0 += zr * cv + zi * sv;
            im0 += zi * cv - zr * sv;
            float zr1 = zp[((h + 1) * 12 + ky) * 2], zi1 = zp[((h + 1) * 12 + ky) * 2 + 1];
            float cv1 = tc[k * 192 + h + 1], sv1 = sgn * ts[k * 192 + h + 1];
            re1 += zr1 * cv1 + zi1 * sv1;
            im1 += zi1 * cv1 - zr1 * sv1;
        }
        ZF[((size_t)bc * 288 + oidx) * 2] = re0 + re1;
        ZF[((size_t)bc * 288 + oidx) * 2 + 1] = im0 + im1;
    }
}

// mode mixing: MO[b,o,mode] = sum_i ZF[b,i,mode]*wt[mode][i][o]
__global__ __launch_bounds__(64) void k_mix(const float* __restrict__ ZF,
                                            const float* __restrict__ wt,
                                            float* __restrict__ MO) {
    int b = blockIdx.x / 288, mode = blockIdx.x % 288;
    __shared__ float zin[64];
    int t = threadIdx.x;
    zin[t] = ZF[(((size_t)b * 32 + (t >> 1)) * 288 + mode) * 2 + (t & 1)];
    __syncthreads();
    int o = t >> 1, ri = t & 1;
    const float* wp = wt + (size_t)mode * 2048;
    float acc = 0.f;
#pragma unroll 8
    for (int i = 0; i < 32; ++i) {
        float ar = zin[2 * i], ai = zin[2 * i + 1];
        float wr = wp[(i * 32 + o) * 2], wi = wp[(i * 32 + o) * 2 + 1];
        acc += ri ? (ar * wi + ai * wr) : (ar * wr - ai * wi);
    }
    MO[(((size_t)b * 32 + o) * 288 + mode) * 2 + ri] = acc;
}

// inverse DFT along H: MO -> Tm[b,o,h,ky]{re,im}, scaled 1/H; also zeroes gn stats
__global__ __launch_bounds__(256) void k_idfth(const float* __restrict__ MO,
                                               const float* __restrict__ tab,
                                               float* __restrict__ Tm,
                                               float* __restrict__ gnstats) {
    if (blockIdx.x == 0 && threadIdx.x < 32) gnstats[threadIdx.x] = 0.f;
    int bo = blockIdx.x;
    __shared__ float mp[576];
    const float* src = MO + (size_t)bo * 576;
    for (int i = threadIdx.x; i < 576; i += 256) mp[i] = src[i];
    __syncthreads();
    const float* tc = tab;
    const float* ts = tab + 2496;
    const float scale = 1.f / 192.f;
    for (int oidx = threadIdx.x; oidx < HHc * 12; oidx += 256) {
        int h = oidx / 12, ky = oidx % 12;
        float re = 0.f, im = 0.f;
#pragma unroll
        for (int j = 0; j < 24; ++j) {
            int k = (j < 12) ? j : 24 - j;
            float sgn = (j < 12) ? 1.f : -1.f;
            float mr = mp[(j * 12 + ky) * 2], mi = mp[(j * 12 + ky) * 2 + 1];
            float cv = tc[k * 192 + h], sv = sgn * ts[k * 192 + h];
            re += mr * cv - mi * sv;
            im += mr * sv + mi * cv;
        }
        Tm[((size_t)bo * HHc + h) * 24 + ky * 2] = re * scale;
        Tm[((size_t)bo * HHc + h) * 24 + ky * 2 + 1] = im * scale;
    }
}

// iDFT-W + y2(1x1 conv) + exact gelu + xi add -> sbuf (= dest F slot); gn1 stats.
// Register-blocked, no LDS staging. use_y1==0 => spectral part is zero (z==0 eval).
__global__ __launch_bounds__(192) void k_f5(const float* __restrict__ z0,
                                            const float* __restrict__ Tm,
                                            const float* __restrict__ xi,
                                            const float* __restrict__ w0w,
                                            const float* __restrict__ w0b,
                                            const float* __restrict__ tab,
                                            float* __restrict__ sbuf,
                                            float* __restrict__ gn1,
                                            int use_y1) {
    int b = blockIdx.x / HHc, h = blockIdx.x % HHc;
    int w = threadIdx.x;
    const float Winv = 1.f / 192.f;
    float acc[32];
    if (use_y1) {
        float cwv[11], swv[11];
#pragma unroll
        for (int ky = 1; ky <= 11; ++ky) {
            cwv[ky - 1] = tab[ky * 192 + w];
            swv[ky - 1] = tab[2496 + ky * 192 + w];
        }
#pragma unroll
        for (int o = 0; o < 32; ++o) {
            const float* tm = Tm + (((size_t)b * 32 + o) * HHc + h) * 24;
            float y1 = tm[0];
#pragma unroll
            for (int ky = 1; ky <= 11; ++ky)
                y1 += 2.f * (tm[2 * ky] * cwv[ky - 1] - tm[2 * ky + 1] * swv[ky - 1]);
            acc[o] = y1 * Winv + w0b[o];
        }
    } else {
#pragma unroll
        for (int o = 0; o < 32; ++o) acc[o] = w0b[o];
    }
    // y2: zv in registers, uniform weight rows -> scalar loads
    const float* zp = z0 + (size_t)b * DDs + (size_t)h * WWc + w;
    float zv[32];
#pragma unroll
    for (int c = 0; c < 32; ++c) zv[c] = zp[(size_t)c * HWc];
#pragma unroll
    for (int o = 0; o < 32; ++o) {
        float a = acc[o];
        const float* row = w0w + o * 32;
#pragma unroll
        for (int c = 0; c < 32; ++c) a += zv[c] * row[c];
        acc[o] = a;
    }
    float s0 = 0.f, q0 = 0.f, s1 = 0.f, q1 = 0.f;
#pragma unroll
    for (int o = 0; o < 32; ++o) {
        float v = acc[o];
        float u = 0.5f * v * (1.f + erff(v * 0.70710678118654752f));
        size_t gi = (size_t)b * DDs + (size_t)o * HWc + (size_t)h * WWc + w;
        float sv = xi[gi] + u;
        sbuf[gi] = sv;
        if (o < 16) { s0 += sv; q0 += sv * sv; }
        else        { s1 += sv; q1 += sv * sv; }
    }
    for (int o = 32; o; o >>= 1) {
        s0 += __shfl_down(s0, o); q0 += __shfl_down(q0, o);
        s1 += __shfl_down(s1, o); q1 += __shfl_down(q1, o);
    }
    __shared__ float red[3][4];
    int wid = threadIdx.x >> 6, lane = threadIdx.x & 63;
    if (lane == 0) { red[wid][0] = s0; red[wid][1] = q0; red[wid][2] = s1; red[wid][3] = q1; }
    __syncthreads();
    if (threadIdx.x == 0) {
        float a0 = 0, a1 = 0, a2 = 0, a3 = 0;
        for (int i = 0; i < 3; ++i) { a0 += red[i][0]; a1 += red[i][1]; a2 += red[i][2]; a3 += red[i][3]; }
        atomicAdd(&gn1[(b * 2 + 0) * 2], a0);
        atomicAdd(&gn1[(b * 2 + 0) * 2 + 1], a1);
        atomicAdd(&gn1[(b * 2 + 1) * 2], a2);
        atomicAdd(&gn1[(b * 2 + 1) * 2 + 1], a3);
    }
}

// buf = relu(z + GN1(buf)) IN PLACE; accumulate gn2 stats; zero gram row/col of slot
__global__ __launch_bounds__(256) void k_f6(const float* __restrict__ z0,
                                            float* buf,
                                            const float* __restrict__ gn1,
                                            const float* __restrict__ n1w,
                                            const float* __restrict__ n1b,
                                            float* __restrict__ gn2,
                                            float* __restrict__ gram,
                                            int slot) {
    if (blockIdx.x == 0 && threadIdx.x < 20) {
        int j = threadIdx.x % 5, b2 = threadIdx.x / 5;
        int ii = slot > j ? slot : j, jj = slot > j ? j : slot;
        gram[b2 * 15 + ii * (ii + 1) / 2 + jj] = 0.f;
    }
    const int binsize = 16 * HWc;
    const int BPB = 128;
    int bin = blockIdx.x / BPB, sub = blockIdx.x % BPB;
    int b = bin >> 1;
    float Nv = (float)binsize;
    float su = gn1[bin * 2], sq = gn1[bin * 2 + 1];
    float mu = su / Nv;
    float var = sq / Nv - mu * mu;
    float inv = rsqrtf(var + EPSc);
    size_t base = (size_t)bin * binsize;
    const float* zb = z0 + (size_t)b * DDs;
    float s = 0.f, q = 0.f;
    for (int i = sub * 256 + threadIdx.x; i < binsize; i += BPB * 256) {
        size_t e = base + i;
        size_t loc = e - (size_t)b * DDs;
        int c = (int)(loc / HWc);
        float sv = buf[e];
        float t = (sv - mu) * inv * n1w[c] + n1b[c];
        float r = zb[loc] + t;
        r = r > 0.f ? r : 0.f;
        buf[e] = r;
        s += r;
        q += r * r;
    }
    for (int o = 32; o; o >>= 1) { s += __shfl_down(s, o); q += __shfl_down(q, o); }
    __shared__ float rs[4], rq[4];
    int wid = threadIdx.x >> 6, lane = threadIdx.x & 63;
    if (lane == 0) { rs[wid] = s; rq[wid] = q; }
    __syncthreads();
    if (threadIdx.x == 0) {
        float ts = rs[0] + rs[1] + rs[2] + rs[3];
        float tq = rq[0] + rq[1] + rq[2] + rq[3];
        atomicAdd(&gn2[bin * 2], ts);
        atomicAdd(&gn2[bin * 2 + 1], tq);
    }
}

// buf = GN2(buf) IN PLACE; G[slot] = buf - z; incremental Gram row/col update.
// grid: 1024 blocks = 4 batches x 256 sub
__global__ __launch_bounds__(256) void k_f7g(float* buf,
                                             const float* __restrict__ z,
                                             const float* __restrict__ gn2,
                                             const float* __restrict__ n2w,
                                             const float* __restrict__ n2b,
                                             float* __restrict__ G,
                                             float* __restrict__ gram,
                                             int slot) {
    int b = blockIdx.x >> 8, sub = blockIdx.x & 255;
    const float Ninv = 1.f / (16.f * HWc);
    float su0 = gn2[(b * 2) * 2], sq0 = gn2[(b * 2) * 2 + 1];
    float mu0 = su0 * Ninv, inv0 = rsqrtf(sq0 * Ninv - mu0 * mu0 + EPSc);
    float su1 = gn2[(b * 2 + 1) * 2], sq1 = gn2[(b * 2 + 1) * 2 + 1];
    float mu1 = su1 * Ninv, inv1 = rsqrtf(sq1 * Ninv - mu1 * mu1 + EPSc);
    size_t base = (size_t)b * DDs;
    float* Gs = G + (size_t)slot * SZ_T;
    float p0 = 0, p1 = 0, p2 = 0, p3 = 0, p4 = 0;
    for (int loc = sub * 256 + threadIdx.x; loc < DDi; loc += 65536) {
        size_t e = base + loc;
        int c = loc / HWc;
        float mu = (c < 16) ? mu0 : mu1;
        float inv = (c < 16) ? inv0 : inv1;
        float fn = (buf[e] - mu) * inv * n2w[c] + n2b[c];
        buf[e] = fn;
        float g = fn - z[e];
        Gs[e] = g;
        float g0 = (slot == 0) ? g : G[e];
        float g1 = (slot == 1) ? g : G[SZ_T + e];
        float g2 = (slot == 2) ? g : G[2 * SZ_T + e];
        float g3 = (slot == 3) ? g : G[3 * SZ_T + e];
        float g4 = (slot == 4) ? g : G[4 * SZ_T + e];
        p0 += g * g0; p1 += g * g1; p2 += g * g2; p3 += g * g3; p4 += g * g4;
    }
    float p[5] = {p0, p1, p2, p3, p4};
    __shared__ float red[4][5];
    int wid = threadIdx.x >> 6, lane = threadIdx.x & 63;
#pragma unroll
    for (int j = 0; j < 5; ++j) {
        float v = p[j];
        for (int o = 32; o; o >>= 1) v += __shfl_down(v, o);
        if (lane == 0) red[wid][j] = v;
    }
    __syncthreads();
    if (threadIdx.x == 0) {
#pragma unroll
        for (int j = 0; j < 5; ++j) {
            int ii = slot > j ? slot : j, jj = slot > j ? j : slot;
            atomicAdd(&gram[b * 15 + ii * (ii + 1) / 2 + jj],
                      red[0][j] + red[1][j] + red[2][j] + red[3][j]);
        }
    }
}

// ---------------- Anderson solve / xnew ----------------
__global__ void k_solve(const float* __restrict__ gram, float* __restrict__ alpha, int n) {
    int b = threadIdx.x;
    if (b >= BBc) return;
    float A[6][7];
    int nn = n + 1;
    for (int i = 0; i < nn; ++i)
        for (int j = 0; j <= nn; ++j) A[i][j] = 0.f;
    for (int j = 1; j < nn; ++j) { A[0][j] = 1.f; A[j][0] = 1.f; }
    for (int i = 0; i < n; ++i)
        for (int j = 0; j < n; ++j) {
            int ii = i > j ? i : j, jj = i > j ? j : i;
            float v = gram[b * 15 + ii * (ii + 1) / 2 + jj];
            A[i + 1][j + 1] = v + ((i == j) ? 1e-4f : 0.f);
        }
    A[0][nn] = 1.f;
    for (int col = 0; col < nn; ++col) {
        int piv = col;
        float best = fabsf(A[col][col]);
        for (int r2 = col + 1; r2 < nn; ++r2) {
            float av = fabsf(A[r2][col]);
            if (av > best) { best = av; piv = r2; }
        }
        if (piv != col)
            for (int c2 = 0; c2 <= nn; ++c2) {
                float tv = A[col][c2];
                A[col][c2] = A[piv][c2];
                A[piv][c2] = tv;
            }
        float d = A[col][col];
        for (int r2 = col + 1; r2 < nn; ++r2) {
            float f = A[r2][col] / d;
            for (int c2 = col; c2 <= nn; ++c2) A[r2][c2] -= f * A[col][c2];
        }
    }
    float sol[6];
    for (int r2 = nn - 1; r2 >= 0; --r2) {
        float v = A[r2][nn];
        for (int c2 = r2 + 1; c2 < nn; ++c2) v -= A[r2][c2] * sol[c2];
        sol[r2] = v / A[r2][r2];
    }
    for (int j = 0; j < 5; ++j) alpha[b * 5 + j] = (j < n) ? sol[j + 1] : 0.f;
}

// xcur = sum_j alpha_j * F[j]
__global__ void k_xnew(const float* __restrict__ F, const float* __restrict__ alpha,
                       float* __restrict__ xcur) {
    int i = blockIdx.x * 256 + threadIdx.x;
    if (i >= (int)SZ_T) return;
    int b = i / DDi;
    const size_t SS = SZ_T;
    float a0 = alpha[b * 5], a1 = alpha[b * 5 + 1], a2 = alpha[b * 5 + 2];
    float a3 = alpha[b * 5 + 3], a4 = alpha[b * 5 + 4];
    xcur[i] = a0 * F[i] + a1 * F[SS + i] + a2 * F[2 * SS + i] +
              a3 * F[3 * SS + i] + a4 * F[4 * SS + i];
}

// ---------------- final: BN stats + BN + fc1(gelu) + fc2 ----------------
__global__ __launch_bounds__(256) void k_bnstats(const float* __restrict__ z,
                                                 float* __restrict__ bstats) {
    const int BPB = 18;
    int c = blockIdx.x / BPB, sub = blockIdx.x % BPB;
    float s = 0.f, q = 0.f;
    for (int i = sub * 256 + threadIdx.x; i < BBc * HWc; i += BPB * 256) {
        int b = i / HWc, hw = i % HWc;
        float v = z[(size_t)b * DDs + (size_t)c * HWc + hw];
        s += v;
        q += v * v;
    }
    for (int o = 32; o; o >>= 1) { s += __shfl_down(s, o); q += __shfl_down(q, o); }
    __shared__ float rs[4], rq[4];
    int wid = threadIdx.x >> 6, lane = threadIdx.x & 63;
    if (lane == 0) { rs[wid] = s; rq[wid] = q; }
    __syncthreads();
    if (threadIdx.x == 0) {
        atomicAdd(&bstats[c * 2], rs[0] + rs[1] + rs[2] + rs[3]);
        atomicAdd(&bstats[c * 2 + 1], rq[0] + rq[1] + rq[2] + rq[3]);
    }
}

__global__ __launch_bounds__(192) void k_final(const float* __restrict__ z,
                                               const float* __restrict__ bstats,
                                               const float* __restrict__ bnw,
                                               const float* __restrict__ bnb,
                                               const float* __restrict__ fc1w,
                                               const float* __restrict__ fc1b,
                                               const float* __restrict__ fc2w,
                                               const float* __restrict__ fc2b,
                                               float* __restrict__ out) {
    int b = blockIdx.x / HHc, h = blockIdx.x % HHc;
    int w = threadIdx.x;
    const float Ninv = 1.f / ((float)BBc * HWc);
    float zv[32];
#pragma unroll
    for (int c = 0; c < 32; ++c) {
        float su = bstats[c * 2], sq = bstats[c * 2 + 1];
        float mu = su * Ninv;
        float var = sq * Ninv - mu * mu;
        float inv = rsqrtf(var + EPSc);
        float v = z[(size_t)b * DDs + (size_t)c * HWc + (size_t)h * WWc + w];
        zv[c] = (v - mu) * inv * bnw[c] + bnb[c];
    }
    float acc2 = fc2b[0];
#pragma unroll
    for (int o = 0; o < 32; ++o) {
        float a = fc1b[o];
        const float* row = fc1w + o * 32;
#pragma unroll
        for (int c = 0; c < 32; ++c) a += zv[c] * row[c];
        float g = 0.5f * a * (1.f + erff(a * 0.70710678118654752f));
        acc2 += fc2w[o] * g;
    }
    out[(size_t)b * HWc + (size_t)h * WWc + w] = acc2;
}

// ---------------- host ----------------
extern "C" void kernel_launch(void* const* d_in, const int* in_sizes, int n_in,
                              void* d_out, int out_size, void* d_ws, size_t ws_size,
                              hipStream_t stream) {
    (void)in_sizes; (void)n_in; (void)out_size; (void)ws_size;
    const float* x    = (const float*)d_in[0];
    const float* fc0w = (const float*)d_in[1];
    const float* fc0b = (const float*)d_in[2];
    const float* convw = (const float*)d_in[3];
    const float* gnw  = (const float*)d_in[4];
    const float* gnb  = (const float*)d_in[5];
    const float* qw   = (const float*)d_in[6];
    const float* qb   = (const float*)d_in[7];
    const float* sw1r = (const float*)d_in[8];
    const float* sw1i = (const float*)d_in[9];
    const float* sw2r = (const float*)d_in[10];
    const float* sw2i = (const float*)d_in[11];
    const float* w0w  = (const float*)d_in[12];
    const float* w0b  = (const float*)d_in[13];
    const float* n1w  = (const float*)d_in[14];
    const float* n1b  = (const float*)d_in[15];
    const float* n2w  = (const float*)d_in[16];
    const float* n2b  = (const float*)d_in[17];
    const float* bnw  = (const float*)d_in[18];
    const float* bnb  = (const float*)d_in[19];
    const float* fc1w = (const float*)d_in[20];
    const float* fc1b = (const float*)d_in[21];
    const float* fc2w = (const float*)d_in[22];
    const float* fc2b = (const float*)d_in[23];
    float* out = (float*)d_out;

    float* ws = (float*)d_ws;
    float* XC  = ws + OFF_XC;
    float* XIp = ws + OFF_XI;
    float* Fb  = ws + OFF_F;
    float* Gb  = ws + OFF_G;
    float* ZC  = ws + OFF_ZC;
    float* ZFp = ws + OFF_ZF;
    float* MOp = ws + OFF_MO;
    float* TM  = ws + OFF_TM;
    float* WT  = ws + OFF_WT;
    float* TAB = ws + OFF_TAB;
    float* ST  = ws + OFF_STAT;
    float* XI0 = ws + A_XI0;   // setup alias (inside G region, dead before f7g)

    const int TBLK = (int)((SZ_T + 255) / 256);  // 18432

    // one f_block evaluation: reads z ([b][D], stride D), writes F slot + G slot + Gram
    auto runf = [&](const float* zin, int outslot, bool zero_input) {
        float* dst = Fb + (size_t)outslot * SZ_T;
        if (!zero_input) {
            k_dftw<<<BBc * CCc * 24, 192, 0, stream>>>(zin, TAB, ZC);
            k_dfth<<<BBc * CCc, 256, 0, stream>>>(ZC, TAB, ZFp);
            k_mix<<<BBc * 288, 64, 0, stream>>>(ZFp, WT, MOp);
            k_idfth<<<BBc * CCc, 256, 0, stream>>>(MOp, TAB, TM, ST + ST_GN1);
        }
        k_f5<<<BBc * HHc, 192, 0, stream>>>(zin, TM, XIp, w0w, w0b, TAB, dst,
                                            ST + ST_GN1, zero_input ? 0 : 1);
        k_f6<<<8 * 128, 256, 0, stream>>>(zin, dst, ST + ST_GN1, n1w, n1b,
                                          ST + ST_GN2, ST + ST_GRAM, outslot);
        k_f7g<<<1024, 256, 0, stream>>>(dst, zin, ST + ST_GN2, n2w, n2b, Gb,
                                        ST + ST_GRAM, outslot);
    };

    // setup
    k_tables<<<10, 256, 0, stream>>>(TAB);
    k_wt<<<(24 * 12 * 1024 + 255) / 256, 256, 0, stream>>>(sw1r, sw1i, sw2r, sw2i, WT);
    k_zero<<<2, 256, 0, stream>>>(ST, 512);
    k_conv<<<BBc * HHc, 192, 0, stream>>>(x, fc0w, fc0b, convw, XI0);
    k_binstats<<<8 * 36, 256, 0, stream>>>(XI0, ST + ST_INJ, 8 * HWc, 36);
    k_xi<<<BBc * HHc, 192, 0, stream>>>(XI0, ST + ST_INJ, gnw, gnb, qw, qb, XIp);
    k_zero<<<TBLK, 256, 0, stream>>>(XC, (int)SZ_T);

    // f0 = f(0) -> F0, G0, Gram(0,*) ; f1 = f(F0) -> F1, G1, Gram(1,*)
    runf(XC, 0, true);
    runf(Fb, 1, false);

    // Anderson iterations k = 2..15
    for (int k = 2; k < 16; ++k) {
        int n = k < 5 ? k : 5;
        int slot = k % 5;
        k_solve<<<1, 64, 0, stream>>>(ST + ST_GRAM, ST + ST_ALPHA, n);
        k_xnew<<<TBLK, 256, 0, stream>>>(Fb, ST + ST_ALPHA, XC);
        runf(XC, slot, false);
    }

    // final z = F slot 0; BatchNorm + fc1(gelu) + fc2
    k_bnstats<<<32 * 18, 256, 0, stream>>>(Fb, ST + ST_BN);
    k_final<<<BBc * HHc, 192, 0, stream>>>(Fb, ST + ST_BN, bnw, bnb, fc1w, fc1b,
                                           fc2w, fc2b, out);
}

// Round 4
// 3858.945 us; speedup vs baseline: 1.1692x; 1.0619x over previous
//
#include <hip/hip_runtime.h>
#include <math.h>

#ifndef M_PI
#define M_PI 3.14159265358979323846
#endif

#define BBc 4
#define CCc 32
#define NRk 16
#define HHc 192
#define WWc 192
#define HWc 36864
#define DDi 1179648
#define M1c 12
#define EPSc 1e-5f

static const size_t DDs = (size_t)DDi;

// ---------------- workspace layout (floats) ----------------
#define SZ_T   ((size_t)4718592)       // B*C*HW  (= B*D)
#define SZ_ZC  ((size_t)589824)        // B*C*H*12*2
#define SZ_ZF  ((size_t)73728)         // B*C*24*12*2
#define SZ_WT  ((size_t)589824)        // 24*12*32*32*2
#define SZ_TAB ((size_t)4992)          // 13*192*2

#define OFF_XC   ((size_t)0)                  // xcur      (B*D)
#define OFF_XI   (OFF_XC + SZ_T)              // xi        (B*D)
#define OFF_F    (OFF_XI + SZ_T)              // F history [slot][B][D], 5 slots
#define OFF_G    (OFF_F + 5 * SZ_T)           // G history [slot][B][D], 5 slots
#define OFF_ZC   (OFF_G + 5 * SZ_T)
#define OFF_ZF   (OFF_ZC + SZ_ZC)
#define OFF_MO   (OFF_ZF + SZ_ZF)
#define OFF_TM   (OFF_MO + SZ_ZF)
#define OFF_WT   (OFF_TM + SZ_ZC)
#define OFF_TAB  (OFF_WT + SZ_WT)
#define OFF_STAT (OFF_TAB + SZ_TAB)
// total ~223.3 MiB (fits ws). setup scratch aliases G region:
#define A_XI0  OFF_G                   // B*16*HW

// stats sublayout (floats within STAT region)
#define ST_GN1   0     // 16
#define ST_GN2   16    // 16
#define ST_INJ   32    // 16
#define ST_BN    48    // 64
#define ST_GRAM  112   // 60  (4 batches x 15 packed lower-tri, PERSISTENT)
#define ST_ALPHA 172   // 20

// ---------------- small utility kernels ----------------
__global__ void k_zero(float* p, int n) {
    int i = blockIdx.x * blockDim.x + threadIdx.x;
    if (i < n) p[i] = 0.f;
}

__global__ void k_tables(float* tab) {
    int i = blockIdx.x * blockDim.x + threadIdx.x;  // 13*192
    if (i < 13 * 192) {
        int k = i / 192, x = i % 192;
        double th = 2.0 * M_PI * (double)(k * x) / 192.0;
        tab[i] = (float)cos(th);
        tab[13 * 192 + i] = (float)sin(th);
    }
}

// transpose spectral weights to wt[j][ky][i][o][2], j in 0..23
__global__ void k_wt(const float* __restrict__ w1r, const float* __restrict__ w1i,
                     const float* __restrict__ w2r, const float* __restrict__ w2i,
                     float* __restrict__ wt) {
    int idx = blockIdx.x * 256 + threadIdx.x;  // 24*12*32*32
    if (idx >= 24 * 12 * 1024) return;
    int o = idx & 31;
    int i = (idx >> 5) & 31;
    int ky = (idx >> 10) % 12;
    int j = idx / (12 * 1024);
    const float* wr;
    const float* wi;
    int x;
    if (j < 12) { wr = w1r; wi = w1i; x = j; }
    else        { wr = w2r; wi = w2i; x = j - 12; }
    int src = ((i * 32 + o) * 12 + x) * 12 + ky;
    size_t dst = (((size_t)j * 12 + ky) * 1024 + i * 32 + o) * 2;
    wt[dst] = wr[src];
    wt[dst + 1] = wi[src];
}

// conv3x3 SAME, (fc0 fused) 1->32->16, block per (b,h), 192 threads
__global__ __launch_bounds__(192) void k_conv(const float* __restrict__ x,
                                              const float* __restrict__ fc0w,
                                              const float* __restrict__ fc0b,
                                              const float* __restrict__ cw,
                                              float* __restrict__ xi0) {
    int b = blockIdx.x / HHc, h = blockIdx.x % HHc;
    __shared__ float sm[3 * 16 * WWc];
    int w = threadIdx.x;
    float acc[16];
#pragma unroll
    for (int n = 0; n < 16; ++n) acc[n] = 0.f;
    for (int cp = 0; cp < 2; ++cp) {
        __syncthreads();
        for (int i = threadIdx.x; i < 3 * 16 * WWc; i += 192) {
            int ww2 = i % WWc;
            int c16 = (i / WWc) % 16;
            int r = i / (WWc * 16);
            int h2 = h + r - 1;
            float v = 0.f;
            if (h2 >= 0 && h2 < HHc) {
                int cc = cp * 16 + c16;
                float xv = x[(size_t)b * HWc + (size_t)h2 * WWc + ww2];
                v = xv * fc0w[cc] + fc0b[cc];
            }
            sm[(r * 16 + c16) * WWc + ww2] = v;
        }
        __syncthreads();
        for (int c16 = 0; c16 < 16; ++c16) {
            const float* r0 = sm + (0 * 16 + c16) * WWc;
            const float* r1 = sm + (1 * 16 + c16) * WWc;
            const float* r2 = sm + (2 * 16 + c16) * WWc;
            float v0 = (w > 0) ? r0[w - 1] : 0.f, v1 = r0[w], v2 = (w < WWc - 1) ? r0[w + 1] : 0.f;
            float v3 = (w > 0) ? r1[w - 1] : 0.f, v4 = r1[w], v5 = (w < WWc - 1) ? r1[w + 1] : 0.f;
            float v6 = (w > 0) ? r2[w - 1] : 0.f, v7 = r2[w], v8 = (w < WWc - 1) ? r2[w + 1] : 0.f;
#pragma unroll
            for (int n = 0; n < 16; ++n) {
                const float* kw = cw + ((n * CCc + cp * 16 + c16) * 9);
                acc[n] += v0 * kw[0] + v1 * kw[1] + v2 * kw[2] + v3 * kw[3] + v4 * kw[4] +
                          v5 * kw[5] + v6 * kw[6] + v7 * kw[7] + v8 * kw[8];
            }
        }
    }
#pragma unroll
    for (int n = 0; n < 16; ++n)
        xi0[((size_t)b * NRk + n) * HWc + (size_t)h * WWc + w] = acc[n];
}

// generic contiguous-bin sum/sumsq with atomics
__global__ void k_binstats(const float* __restrict__ src, float* __restrict__ stats,
                           int binsize, int blocksPerBin) {
    int bin = blockIdx.x / blocksPerBin, sub = blockIdx.x % blocksPerBin;
    const float* p = src + (size_t)bin * binsize;
    float s = 0.f, q = 0.f;
    for (int i = sub * blockDim.x + threadIdx.x; i < binsize; i += blocksPerBin * blockDim.x) {
        float v = p[i];
        s += v;
        q += v * v;
    }
    for (int o = 32; o; o >>= 1) { s += __shfl_down(s, o); q += __shfl_down(q, o); }
    __shared__ float rs[4], rq[4];
    int wid = threadIdx.x >> 6, lane = threadIdx.x & 63;
    if (lane == 0) { rs[wid] = s; rq[wid] = q; }
    __syncthreads();
    if (threadIdx.x == 0) {
        int nw = blockDim.x >> 6;
        float ts = 0.f, tq = 0.f;
        for (int i = 0; i < nw; ++i) { ts += rs[i]; tq += rq[i]; }
        atomicAdd(&stats[bin * 2], ts);
        atomicAdd(&stats[bin * 2 + 1], tq);
    }
}

// xi = sigmoid(q_w * GN(xi0) + q_b), block per (b,h), register-blocked
__global__ __launch_bounds__(192) void k_xi(const float* __restrict__ xi0,
                                            const float* __restrict__ stats,
                                            const float* __restrict__ gnw, const float* __restrict__ gnb,
                                            const float* __restrict__ qw, const float* __restrict__ qb,
                                            float* __restrict__ xi) {
    int b = blockIdx.x / HHc, h = blockIdx.x % HHc;
    int w = threadIdx.x;
    const float Ninv = 1.f / (8.f * HWc);
    float tn[16];
#pragma unroll
    for (int n = 0; n < 16; ++n) {
        int g = n >> 3;
        float su = stats[(b * 2 + g) * 2], sq = stats[(b * 2 + g) * 2 + 1];
        float mu = su * Ninv;
        float var = sq * Ninv - mu * mu;
        float inv = rsqrtf(var + EPSc);
        float v = xi0[((size_t)b * NRk + n) * HWc + (size_t)h * WWc + w];
        tn[n] = (v - mu) * inv * gnw[n] + gnb[n];
    }
#pragma unroll
    for (int d = 0; d < 32; ++d) {
        float acc = qb[d];
        const float* row = qw + d * 16;
#pragma unroll
        for (int n = 0; n < 16; ++n) acc += tn[n] * row[n];
        xi[((size_t)b * CCc + d) * HWc + (size_t)h * WWc + w] = 1.f / (1.f + expf(-acc));
    }
}

// ---------------- f_block kernels (z input: [b][D], batch stride D) ----------------
// forward DFT along W: z -> Zc[b,c,h,ky]{re,im}, ky 0..11. float4 staging.
__global__ __launch_bounds__(192) void k_dftw(const float* __restrict__ z0,
                                              const float* __restrict__ tab,
                                              float* __restrict__ Zc) {
    int bc = blockIdx.x / 24;
    int hg = blockIdx.x % 24;
    int b = bc >> 5, c = bc & 31;
    const float* zp = z0 + (size_t)b * DDs + (size_t)c * HWc + (size_t)hg * 8 * WWc;
    __shared__ float rows[8 * 196];
    __shared__ float tb[24 * 196];
    const float4* zq = (const float4*)zp;
    for (int i4 = threadIdx.x; i4 < 384; i4 += 192) {
        float4 v = zq[i4];
        int r = i4 / 48, col = (i4 % 48) * 4;
        *(float4*)&rows[r * 196 + col] = v;
    }
    for (int i4 = threadIdx.x; i4 < 1152; i4 += 192) {
        int rr = i4 / 48, col = (i4 % 48) * 4;
        const float* src = (rr < 12) ? &tab[rr * 192 + col] : &tab[2496 + (rr - 12) * 192 + col];
        *(float4*)&tb[rr * 196 + col] = *(const float4*)src;
    }
    __syncthreads();
    int t = threadIdx.x;
    int r = t / 24, q = t % 24, ky = q >> 1, isim = q & 1;
    const float* tbp = tb + (isim ? (12 + ky) * 196 : ky * 196);
    const float* rowp = rows + r * 196;
    float a0 = 0.f, a1 = 0.f, a2 = 0.f, a3 = 0.f;
#pragma unroll
    for (int w2 = 0; w2 < WWc; w2 += 4) {
        a0 += rowp[w2] * tbp[w2];
        a1 += rowp[w2 + 1] * tbp[w2 + 1];
        a2 += rowp[w2 + 2] * tbp[w2 + 2];
        a3 += rowp[w2 + 3] * tbp[w2 + 3];
    }
    float acc = (a0 + a1) + (a2 + a3);
    if (isim) acc = -acc;
    int h = hg * 8 + r;
    Zc[(((size_t)bc * HHc + h) * M1c + ky) * 2 + isim] = acc;
}

// forward DFT along H (24 freqs): Zc -> ZF[b,c,j,ky]{re,im}
__global__ __launch_bounds__(256) void k_dfth(const float* __restrict__ Zc,
                                              const float* __restrict__ tab,
                                              float* __restrict__ ZF) {
    int bc = blockIdx.x;
    __shared__ float zp[HHc * 12 * 2];
    const float4* src = (const float4*)(Zc + (size_t)bc * HHc * 12 * 2);
    for (int i4 = threadIdx.x; i4 < HHc * 6; i4 += 256)
        *(float4*)&zp[i4 * 4] = src[i4];
    __syncthreads();
    const float* tc = tab;
    const float* ts = tab + 2496;
    for (int oidx = threadIdx.x; oidx < 288; oidx += 256) {
        int j = oidx / 12, ky = oidx % 12;
        int k = (j < 12) ? j : 24 - j;
        float sgn = (j < 12) ? 1.f : -1.f;
        float re0 = 0.f, im0 = 0.f, re1 = 0.f, im1 = 0.f;
        for (int h = 0; h < HHc; h += 2) {
            float zr = zp[(h * 12 + ky) * 2], zi = zp[(h * 12 + ky) * 2 + 1];
            float cv = tc[k * 192 + h], sv = sgn * ts[k * 192 + h];
            re0 += zr * cv + zi * sv;
            im0 += zi * cv - zr * sv;
            float zr1 = zp[((h + 1) * 12 + ky) * 2], zi1 = zp[((h + 1) * 12 + ky) * 2 + 1];
            float cv1 = tc[k * 192 + h + 1], sv1 = sgn * ts[k * 192 + h + 1];
            re1 += zr1 * cv1 + zi1 * sv1;
            im1 += zi1 * cv1 - zr1 * sv1;
        }
        ZF[((size_t)bc * 288 + oidx) * 2] = re0 + re1;
        ZF[((size_t)bc * 288 + oidx) * 2 + 1] = im0 + im1;
    }
}

// mode mixing: MO[b,o,mode] = sum_i ZF[b,i,mode]*wt[mode][i][o]
__global__ __launch_bounds__(64) void k_mix(const float* __restrict__ ZF,
                                            const float* __restrict__ wt,
                                            float* __restrict__ MO) {
    int b = blockIdx.x / 288, mode = blockIdx.x % 288;
    __shared__ float zin[64];
    int t = threadIdx.x;
    zin[t] = ZF[(((size_t)b * 32 + (t >> 1)) * 288 + mode) * 2 + (t & 1)];
    __syncthreads();
    int o = t >> 1, ri = t & 1;
    const float* wp = wt + (size_t)mode * 2048;
    float acc = 0.f;
#pragma unroll 8
    for (int i = 0; i < 32; ++i) {
        float ar = zin[2 * i], ai = zin[2 * i + 1];
        float wr = wp[(i * 32 + o) * 2], wi = wp[(i * 32 + o) * 2 + 1];
        acc += ri ? (ar * wi + ai * wr) : (ar * wr - ai * wi);
    }
    MO[(((size_t)b * 32 + o) * 288 + mode) * 2 + ri] = acc;
}

// inverse DFT along H: MO -> Tm[b,o,h,ky]{re,im}, scaled 1/H; also zeroes gn stats
__global__ __launch_bounds__(256) void k_idfth(const float* __restrict__ MO,
                                               const float* __restrict__ tab,
                                               float* __restrict__ Tm,
                                               float* __restrict__ gnstats) {
    if (blockIdx.x == 0 && threadIdx.x < 32) gnstats[threadIdx.x] = 0.f;
    int bo = blockIdx.x;
    __shared__ float mp[576];
    const float4* src = (const float4*)(MO + (size_t)bo * 576);
    for (int i4 = threadIdx.x; i4 < 144; i4 += 256)
        *(float4*)&mp[i4 * 4] = src[i4];
    __syncthreads();
    const float* tc = tab;
    const float* ts = tab + 2496;
    const float scale = 1.f / 192.f;
    for (int oidx = threadIdx.x; oidx < HHc * 12; oidx += 256) {
        int h = oidx / 12, ky = oidx % 12;
        float re = 0.f, im = 0.f;
#pragma unroll
        for (int j = 0; j < 24; ++j) {
            int k = (j < 12) ? j : 24 - j;
            float sgn = (j < 12) ? 1.f : -1.f;
            float mr = mp[(j * 12 + ky) * 2], mi = mp[(j * 12 + ky) * 2 + 1];
            float cv = tc[k * 192 + h], sv = sgn * ts[k * 192 + h];
            re += mr * cv - mi * sv;
            im += mr * sv + mi * cv;
        }
        Tm[((size_t)bo * HHc + h) * 24 + ky * 2] = re * scale;
        Tm[((size_t)bo * HHc + h) * 24 + ky * 2 + 1] = im * scale;
    }
}

// iDFT-W + y2(1x1 conv) + exact gelu + xi add -> sbuf (= dest F slot); gn1 stats.
// block = (b, h, og): og-half of channels; 192 threads = 48 w-quads x 4 o-subgroups.
// All global streams float4. z tile + Tm + w0 staged in LDS.
__global__ __launch_bounds__(192) void k_f5(const float* __restrict__ z0,
                                            const float* __restrict__ Tm,
                                            const float* __restrict__ xi,
                                            const float* __restrict__ w0w,
                                            const float* __restrict__ w0b,
                                            const float* __restrict__ tab,
                                            float* __restrict__ sbuf,
                                            float* __restrict__ gn1,
                                            int use_y1) {
    int bi = blockIdx.x;
    int og = bi & 1;
    int h = (bi >> 1) % HHc;
    int b = (bi >> 1) / HHc;
    __shared__ float zl[32 * WWc];     // 24 KB z tile (all 32 c)
    __shared__ float w0s[16 * 32];     // this block's 16 w0 rows
    __shared__ float tms[16 * 24];     // this block's 16 Tm rows
    __shared__ float red[3][2];
    int tid = threadIdx.x;
    // stage z tile (contiguous per c-row), float4
    {
        const float* zp = z0 + (size_t)b * DDs + (size_t)h * WWc;
        for (int i4 = tid; i4 < 32 * 48; i4 += 192) {
            int c = i4 / 48, q = (i4 % 48) * 4;
            float4 v = *(const float4*)(zp + (size_t)c * HWc + q);
            *(float4*)&zl[c * WWc + q] = v;
        }
    }
    // stage w0 rows og*16..og*16+15
    for (int i4 = tid; i4 < 128; i4 += 192) {
        int oo = i4 / 8, q = (i4 % 8) * 4;
        *(float4*)&w0s[oo * 32 + q] = *(const float4*)(w0w + (og * 16 + oo) * 32 + q);
    }
    // stage Tm rows (24 floats each) for the 16 channels
    if (use_y1) {
        for (int i4 = tid; i4 < 96; i4 += 192) {
            int oo = i4 / 6, q = (i4 % 6) * 4;
            int o = og * 16 + oo;
            *(float4*)&tms[oo * 24 + q] =
                *(const float4*)(Tm + (((size_t)b * 32 + o) * HHc + h) * 24 + q);
        }
    }
    __syncthreads();

    int wq = tid >> 2;          // 0..47
    int oq = tid & 3;           // 0..3
    int w4 = wq * 4;
    int lo0 = oq * 4;           // local o base (0..12)
    const float Winv = 1.f / 192.f;
    float acc[4][4];
#pragma unroll
    for (int oo = 0; oo < 4; ++oo) {
        float bbv = w0b[og * 16 + lo0 + oo];
#pragma unroll
        for (int k = 0; k < 4; ++k) acc[oo][k] = bbv;
    }
    if (use_y1) {
        // ky = 0 term
#pragma unroll
        for (int oo = 0; oo < 4; ++oo) {
            float t0 = tms[(lo0 + oo) * 24];
#pragma unroll
            for (int k = 0; k < 4; ++k) acc[oo][k] += t0 * Winv;
        }
#pragma unroll
        for (int ky = 1; ky <= 11; ++ky) {
            float4 c4 = *(const float4*)(tab + ky * 192 + w4);
            float4 s4 = *(const float4*)(tab + 2496 + ky * 192 + w4);
            float sc = 2.f * Winv;
#pragma unroll
            for (int oo = 0; oo < 4; ++oo) {
                float tre = tms[(lo0 + oo) * 24 + 2 * ky] * sc;
                float tim = tms[(lo0 + oo) * 24 + 2 * ky + 1] * sc;
                acc[oo][0] += tre * c4.x - tim * s4.x;
                acc[oo][1] += tre * c4.y - tim * s4.y;
                acc[oo][2] += tre * c4.z - tim * s4.z;
                acc[oo][3] += tre * c4.w - tim * s4.w;
            }
        }
    }
    // y2: 1x1 conv over all 32 channels from LDS tile
#pragma unroll 8
    for (int c = 0; c < 32; ++c) {
        float4 zq4 = *(const float4*)&zl[c * WWc + w4];
#pragma unroll
        for (int oo = 0; oo < 4; ++oo) {
            float wv = w0s[(lo0 + oo) * 32 + c];
            acc[oo][0] += zq4.x * wv;
            acc[oo][1] += zq4.y * wv;
            acc[oo][2] += zq4.z * wv;
            acc[oo][3] += zq4.w * wv;
        }
    }
    // gelu + xi + store + stats
    float s = 0.f, q = 0.f;
#pragma unroll
    for (int oo = 0; oo < 4; ++oo) {
        int o = og * 16 + lo0 + oo;
        size_t gi = (size_t)b * DDs + (size_t)o * HWc + (size_t)h * WWc + w4;
        float4 x4 = *(const float4*)(xi + gi);
        float4 out4;
        float* op = (float*)&out4;
        const float* xp = (const float*)&x4;
#pragma unroll
        for (int k = 0; k < 4; ++k) {
            float v = acc[oo][k];
            float u = 0.5f * v * (1.f + erff(v * 0.70710678118654752f));
            float sv = xp[k] + u;
            op[k] = sv;
            s += sv;
            q += sv * sv;
        }
        *(float4*)(sbuf + gi) = out4;
    }
    for (int o = 32; o; o >>= 1) { s += __shfl_down(s, o); q += __shfl_down(q, o); }
    int wid = tid >> 6, lane = tid & 63;
    if (lane == 0) { red[wid][0] = s; red[wid][1] = q; }
    __syncthreads();
    if (tid == 0) {
        float a0 = red[0][0] + red[1][0] + red[2][0];
        float a1 = red[0][1] + red[1][1] + red[2][1];
        atomicAdd(&gn1[(b * 2 + og) * 2], a0);
        atomicAdd(&gn1[(b * 2 + og) * 2 + 1], a1);
    }
}

// buf = relu(z + GN1(buf)) IN PLACE (float4); accumulate gn2 stats; zero gram row/col
// grid: 8 bins x 144 blocks of 256 threads; each thread 4 quads (strided)
__global__ __launch_bounds__(256) void k_f6(const float* __restrict__ z0,
                                            float* buf,
                                            const float* __restrict__ gn1,
                                            const float* __restrict__ n1w,
                                            const float* __restrict__ n1b,
                                            float* __restrict__ gn2,
                                            float* __restrict__ gram,
                                            int slot) {
    if (blockIdx.x == 0 && threadIdx.x < 20) {
        int j = threadIdx.x % 5, b2 = threadIdx.x / 5;
        int ii = slot > j ? slot : j, jj = slot > j ? j : slot;
        gram[b2 * 15 + ii * (ii + 1) / 2 + jj] = 0.f;
    }
    const int binq = 147456;         // quads per bin (16*HWc/4)
    int bin = blockIdx.x / 144, sub = blockIdx.x % 144;
    float Nv = 16.f * HWc;
    float su = gn1[bin * 2], sq = gn1[bin * 2 + 1];
    float mu = su / Nv;
    float var = sq / Nv - mu * mu;
    float inv = rsqrtf(var + EPSc);
    const float4* z4 = (const float4*)z0;
    float4* b4 = (float4*)buf;
    float s = 0.f, q = 0.f;
    for (int i4 = sub * 256 + threadIdx.x; i4 < binq; i4 += 36864) {
        int e4 = bin * binq + i4;
        int c = (bin & 1) * 16 + i4 / 9216;    // 9216 = HWc/4
        float w1 = inv * n1w[c];
        float b1 = n1b[c] - mu * w1;
        float4 sv = b4[e4];
        float4 zv = z4[e4];
        float4 r;
        r.x = zv.x + sv.x * w1 + b1; r.x = r.x > 0.f ? r.x : 0.f;
        r.y = zv.y + sv.y * w1 + b1; r.y = r.y > 0.f ? r.y : 0.f;
        r.z = zv.z + sv.z * w1 + b1; r.z = r.z > 0.f ? r.z : 0.f;
        r.w = zv.w + sv.w * w1 + b1; r.w = r.w > 0.f ? r.w : 0.f;
        b4[e4] = r;
        s += r.x + r.y + r.z + r.w;
        q += r.x * r.x + r.y * r.y + r.z * r.z + r.w * r.w;
    }
    for (int o = 32; o; o >>= 1) { s += __shfl_down(s, o); q += __shfl_down(q, o); }
    __shared__ float rs[4], rq[4];
    int wid = threadIdx.x >> 6, lane = threadIdx.x & 63;
    if (lane == 0) { rs[wid] = s; rq[wid] = q; }
    __syncthreads();
    if (threadIdx.x == 0) {
        atomicAdd(&gn2[bin * 2], rs[0] + rs[1] + rs[2] + rs[3]);
        atomicAdd(&gn2[bin * 2 + 1], rq[0] + rq[1] + rq[2] + rq[3]);
    }
}

// buf = GN2(buf) IN PLACE; G[slot] = buf - z; incremental Gram row/col (float4).
// grid: 4 b x 288 sub = 1152 blocks of 256
__global__ __launch_bounds__(256) void k_f7g(float* buf,
                                             const float* __restrict__ z,
                                             const float* __restrict__ gn2,
                                             const float* __restrict__ n2w,
                                             const float* __restrict__ n2b,
                                             float* __restrict__ G,
                                             float* __restrict__ gram,
                                             int slot) {
    int b = blockIdx.x / 288, sub = blockIdx.x % 288;
    const float Ninv = 1.f / (16.f * HWc);
    float su0 = gn2[(b * 2) * 2], sq0 = gn2[(b * 2) * 2 + 1];
    float mu0 = su0 * Ninv, inv0 = rsqrtf(sq0 * Ninv - mu0 * mu0 + EPSc);
    float su1 = gn2[(b * 2 + 1) * 2], sq1 = gn2[(b * 2 + 1) * 2 + 1];
    float mu1 = su1 * Ninv, inv1 = rsqrtf(sq1 * Ninv - mu1 * mu1 + EPSc);
    const int bq = 294912;   // quads per batch (DDi/4)
    const int sq4 = 1179648; // quads per G slot (SZ_T/4)
    float4* b4 = (float4*)buf;
    const float4* z4 = (const float4*)z;
    float4* G4 = (float4*)G;
    float p0 = 0, p1 = 0, p2 = 0, p3 = 0, p4 = 0;
    for (int loc4 = sub * 256 + threadIdx.x; loc4 < bq; loc4 += 73728) {
        int e4 = b * bq + loc4;
        int c = loc4 / 9216;
        float mu = (c < 16) ? mu0 : mu1;
        float inv = (c < 16) ? inv0 : inv1;
        float wv = inv * n2w[c];
        float bv = n2b[c] - mu * wv;
        float4 r = b4[e4];
        float4 zv = z4[e4];
        float4 fn, g;
        fn.x = r.x * wv + bv; g.x = fn.x - zv.x;
        fn.y = r.y * wv + bv; g.y = fn.y - zv.y;
        fn.z = r.z * wv + bv; g.z = fn.z - zv.z;
        fn.w = r.w * wv + bv; g.w = fn.w - zv.w;
        b4[e4] = fn;
        G4[(size_t)slot * sq4 + e4] = g;
        float4 g0 = (slot == 0) ? g : G4[e4];
        float4 g1 = (slot == 1) ? g : G4[sq4 + e4];
        float4 g2 = (slot == 2) ? g : G4[2 * sq4 + e4];
        float4 g3 = (slot == 3) ? g : G4[3 * sq4 + e4];
        float4 g4v = (slot == 4) ? g : G4[4 * sq4 + e4];
        p0 += g.x * g0.x + g.y * g0.y + g.z * g0.z + g.w * g0.w;
        p1 += g.x * g1.x + g.y * g1.y + g.z * g1.z + g.w * g1.w;
        p2 += g.x * g2.x + g.y * g2.y + g.z * g2.z + g.w * g2.w;
        p3 += g.x * g3.x + g.y * g3.y + g.z * g3.z + g.w * g3.w;
        p4 += g.x * g4v.x + g.y * g4v.y + g.z * g4v.z + g.w * g4v.w;
    }
    float p[5] = {p0, p1, p2, p3, p4};
    __shared__ float red[4][5];
    int wid = threadIdx.x >> 6, lane = threadIdx.x & 63;
#pragma unroll
    for (int j = 0; j < 5; ++j) {
        float v = p[j];
        for (int o = 32; o; o >>= 1) v += __shfl_down(v, o);
        if (lane == 0) red[wid][j] = v;
    }
    __syncthreads();
    if (threadIdx.x == 0) {
#pragma unroll
        for (int j = 0; j < 5; ++j) {
            int ii = slot > j ? slot : j, jj = slot > j ? j : slot;
            atomicAdd(&gram[b * 15 + ii * (ii + 1) / 2 + jj],
                      red[0][j] + red[1][j] + red[2][j] + red[3][j]);
        }
    }
}

// ---------------- Anderson solve / xnew ----------------
__global__ void k_solve(const float* __restrict__ gram, float* __restrict__ alpha, int n) {
    int b = threadIdx.x;
    if (b >= BBc) return;
    float A[6][7];
    int nn = n + 1;
    for (int i = 0; i < nn; ++i)
        for (int j = 0; j <= nn; ++j) A[i][j] = 0.f;
    for (int j = 1; j < nn; ++j) { A[0][j] = 1.f; A[j][0] = 1.f; }
    for (int i = 0; i < n; ++i)
        for (int j = 0; j < n; ++j) {
            int ii = i > j ? i : j, jj = i > j ? j : i;
            float v = gram[b * 15 + ii * (ii + 1) / 2 + jj];
            A[i + 1][j + 1] = v + ((i == j) ? 1e-4f : 0.f);
        }
    A[0][nn] = 1.f;
    for (int col = 0; col < nn; ++col) {
        int piv = col;
        float best = fabsf(A[col][col]);
        for (int r2 = col + 1; r2 < nn; ++r2) {
            float av = fabsf(A[r2][col]);
            if (av > best) { best = av; piv = r2; }
        }
        if (piv != col)
            for (int c2 = 0; c2 <= nn; ++c2) {
                float tv = A[col][c2];
                A[col][c2] = A[piv][c2];
                A[piv][c2] = tv;
            }
        float d = A[col][col];
        for (int r2 = col + 1; r2 < nn; ++r2) {
            float f = A[r2][col] / d;
            for (int c2 = col; c2 <= nn; ++c2) A[r2][c2] -= f * A[col][c2];
        }
    }
    float sol[6];
    for (int r2 = nn - 1; r2 >= 0; --r2) {
        float v = A[r2][nn];
        for (int c2 = r2 + 1; c2 < nn; ++c2) v -= A[r2][c2] * sol[c2];
        sol[r2] = v / A[r2][r2];
    }
    for (int j = 0; j < 5; ++j) alpha[b * 5 + j] = (j < n) ? sol[j + 1] : 0.f;
}

// xcur = sum_j alpha_j * F[j]  (float4)
__global__ __launch_bounds__(256) void k_xnew(const float* __restrict__ F,
                                              const float* __restrict__ alpha,
                                              float* __restrict__ xcur) {
    int i4 = blockIdx.x * 256 + threadIdx.x;
    if (i4 >= (int)(SZ_T / 4)) return;
    int b = i4 / 294912;
    const int sq4 = 1179648;
    float a0 = alpha[b * 5], a1 = alpha[b * 5 + 1], a2 = alpha[b * 5 + 2];
    float a3 = alpha[b * 5 + 3], a4 = alpha[b * 5 + 4];
    const float4* F4 = (const float4*)F;
    float4 f0 = F4[i4], f1 = F4[sq4 + i4], f2 = F4[2 * sq4 + i4],
           f3 = F4[3 * sq4 + i4], f4 = F4[4 * sq4 + i4];
    float4 r;
    r.x = a0 * f0.x + a1 * f1.x + a2 * f2.x + a3 * f3.x + a4 * f4.x;
    r.y = a0 * f0.y + a1 * f1.y + a2 * f2.y + a3 * f3.y + a4 * f4.y;
    r.z = a0 * f0.z + a1 * f1.z + a2 * f2.z + a3 * f3.z + a4 * f4.z;
    r.w = a0 * f0.w + a1 * f1.w + a2 * f2.w + a3 * f3.w + a4 * f4.w;
    ((float4*)xcur)[i4] = r;
}

// ---------------- final: BN stats + BN + fc1(gelu) + fc2 ----------------
__global__ __launch_bounds__(256) void k_bnstats(const float* __restrict__ z,
                                                 float* __restrict__ bstats) {
    const int BPB = 18;
    int c = blockIdx.x / BPB, sub = blockIdx.x % BPB;
    float s = 0.f, q = 0.f;
    for (int i = sub * 256 + threadIdx.x; i < BBc * HWc; i += BPB * 256) {
        int b = i / HWc, hw = i % HWc;
        float v = z[(size_t)b * DDs + (size_t)c * HWc + hw];
        s += v;
        q += v * v;
    }
    for (int o = 32; o; o >>= 1) { s += __shfl_down(s, o); q += __shfl_down(q, o); }
    __shared__ float rs[4], rq[4];
    int wid = threadIdx.x >> 6, lane = threadIdx.x & 63;
    if (lane == 0) { rs[wid] = s; rq[wid] = q; }
    __syncthreads();
    if (threadIdx.x == 0) {
        atomicAdd(&bstats[c * 2], rs[0] + rs[1] + rs[2] + rs[3]);
        atomicAdd(&bstats[c * 2 + 1], rq[0] + rq[1] + rq[2] + rq[3]);
    }
}

__global__ __launch_bounds__(192) void k_final(const float* __restrict__ z,
                                               const float* __restrict__ bstats,
                                               const float* __restrict__ bnw,
                                               const float* __restrict__ bnb,
                                               const float* __restrict__ fc1w,
                                               const float* __restrict__ fc1b,
                                               const float* __restrict__ fc2w,
                                               const float* __restrict__ fc2b,
                                               float* __restrict__ out) {
    int b = blockIdx.x / HHc, h = blockIdx.x % HHc;
    int w = threadIdx.x;
    const float Ninv = 1.f / ((float)BBc * HWc);
    float zv[32];
#pragma unroll
    for (int c = 0; c < 32; ++c) {
        float su = bstats[c * 2], sq = bstats[c * 2 + 1];
        float mu = su * Ninv;
        float var = sq * Ninv - mu * mu;
        float inv = rsqrtf(var + EPSc);
        float v = z[(size_t)b * DDs + (size_t)c * HWc + (size_t)h * WWc + w];
        zv[c] = (v - mu) * inv * bnw[c] + bnb[c];
    }
    float acc2 = fc2b[0];
#pragma unroll
    for (int o = 0; o < 32; ++o) {
        float a = fc1b[o];
        const float* row = fc1w + o * 32;
#pragma unroll
        for (int c = 0; c < 32; ++c) a += zv[c] * row[c];
        float g = 0.5f * a * (1.f + erff(a * 0.70710678118654752f));
        acc2 += fc2w[o] * g;
    }
    out[(size_t)b * HWc + (size_t)h * WWc + w] = acc2;
}

// ---------------- host ----------------
extern "C" void kernel_launch(void* const* d_in, const int* in_sizes, int n_in,
                              void* d_out, int out_size, void* d_ws, size_t ws_size,
                              hipStream_t stream) {
    (void)in_sizes; (void)n_in; (void)out_size; (void)ws_size;
    const float* x    = (const float*)d_in[0];
    const float* fc0w = (const float*)d_in[1];
    const float* fc0b = (const float*)d_in[2];
    const float* convw = (const float*)d_in[3];
    const float* gnw  = (const float*)d_in[4];
    const float* gnb  = (const float*)d_in[5];
    const float* qw   = (const float*)d_in[6];
    const float* qb   = (const float*)d_in[7];
    const float* sw1r = (const float*)d_in[8];
    const float* sw1i = (const float*)d_in[9];
    const float* sw2r = (const float*)d_in[10];
    const float* sw2i = (const float*)d_in[11];
    const float* w0w  = (const float*)d_in[12];
    const float* w0b  = (const float*)d_in[13];
    const float* n1w  = (const float*)d_in[14];
    const float* n1b  = (const float*)d_in[15];
    const float* n2w  = (const float*)d_in[16];
    const float* n2b  = (const float*)d_in[17];
    const float* bnw  = (const float*)d_in[18];
    const float* bnb  = (const float*)d_in[19];
    const float* fc1w = (const float*)d_in[20];
    const float* fc1b = (const float*)d_in[21];
    const float* fc2w = (const float*)d_in[22];
    const float* fc2b = (const float*)d_in[23];
    float* out = (float*)d_out;

    float* ws = (float*)d_ws;
    float* XC  = ws + OFF_XC;
    float* XIp = ws + OFF_XI;
    float* Fb  = ws + OFF_F;
    float* Gb  = ws + OFF_G;
    float* ZC  = ws + OFF_ZC;
    float* ZFp = ws + OFF_ZF;
    float* MOp = ws + OFF_MO;
    float* TM  = ws + OFF_TM;
    float* WT  = ws + OFF_WT;
    float* TAB = ws + OFF_TAB;
    float* ST  = ws + OFF_STAT;
    float* XI0 = ws + A_XI0;   // setup alias (inside G region, dead before f7g)

    const int TBLK = (int)((SZ_T + 255) / 256);  // 18432

    // one f_block evaluation: reads z ([b][D], stride D), writes F slot + G slot + Gram
    auto runf = [&](const float* zin, int outslot, bool zero_input) {
        float* dst = Fb + (size_t)outslot * SZ_T;
        if (!zero_input) {
            k_dftw<<<BBc * CCc * 24, 192, 0, stream>>>(zin, TAB, ZC);
            k_dfth<<<BBc * CCc, 256, 0, stream>>>(ZC, TAB, ZFp);
            k_mix<<<BBc * 288, 64, 0, stream>>>(ZFp, WT, MOp);
            k_idfth<<<BBc * CCc, 256, 0, stream>>>(MOp, TAB, TM, ST + ST_GN1);
        }
        k_f5<<<BBc * HHc * 2, 192, 0, stream>>>(zin, TM, XIp, w0w, w0b, TAB, dst,
                                                ST + ST_GN1, zero_input ? 0 : 1);
        k_f6<<<8 * 144, 256, 0, stream>>>(zin, dst, ST + ST_GN1, n1w, n1b,
                                          ST + ST_GN2, ST + ST_GRAM, outslot);
        k_f7g<<<BBc * 288, 256, 0, stream>>>(dst, zin, ST + ST_GN2, n2w, n2b, Gb,
                                             ST + ST_GRAM, outslot);
    };

    // setup
    k_tables<<<10, 256, 0, stream>>>(TAB);
    k_wt<<<(24 * 12 * 1024 + 255) / 256, 256, 0, stream>>>(sw1r, sw1i, sw2r, sw2i, WT);
    k_zero<<<2, 256, 0, stream>>>(ST, 512);
    k_conv<<<BBc * HHc, 192, 0, stream>>>(x, fc0w, fc0b, convw, XI0);
    k_binstats<<<8 * 36, 256, 0, stream>>>(XI0, ST + ST_INJ, 8 * HWc, 36);
    k_xi<<<BBc * HHc, 192, 0, stream>>>(XI0, ST + ST_INJ, gnw, gnb, qw, qb, XIp);
    k_zero<<<TBLK, 256, 0, stream>>>(XC, (int)SZ_T);

    // f0 = f(0) -> F0, G0, Gram(0,*) ; f1 = f(F0) -> F1, G1, Gram(1,*)
    runf(XC, 0, true);
    runf(Fb, 1, false);

    // Anderson iterations k = 2..15
    for (int k = 2; k < 16; ++k) {
        int n = k < 5 ? k : 5;
        int slot = k % 5;
        k_solve<<<1, 64, 0, stream>>>(ST + ST_GRAM, ST + ST_ALPHA, n);
        k_xnew<<<(int)(SZ_T / 4 + 255) / 256, 256, 0, stream>>>(Fb, ST + ST_ALPHA, XC);
        runf(XC, slot, false);
    }

    // final z = F slot 0; BatchNorm + fc1(gelu) + fc2
    k_bnstats<<<32 * 18, 256, 0, stream>>>(Fb, ST + ST_BN);
    k_final<<<BBc * HHc, 192, 0, stream>>>(Fb, ST + ST_BN, bnw, bnb, fc1w, fc1b,
                                           fc2w, fc2b, out);
}